// Round 2
// baseline (3009.050 us; speedup 1.0000x reference)
//
#include <hip/hip_runtime.h>
#include <math.h>

// ---------------------------------------------------------------------------
// RPN GMM head, MI355X. Round 8: all-variant conv blocks.
// Post-mortem R6/R7: dur == (FETCH+WRITE)/~3TB/s, and WRITE was 13-20x the
// hand-counted output -> scratch spill (acc[2][4][4]=128 AGPR pinned the full
// 2-wave register budget; staging/compute temps spilled). Fix is structural:
//  - one block = one 16x8 tile x one batch x ALL (job,ocHalf) variants run
//    sequentially. acc is now 32 AGPR/wave -> no spill pressure.
//  - full-depth input (10x18x256ic = 92KB) staged ONCE via global_load_lds
//    into 127KB static LDS; input HBM traffic x1 (was x4 via sharer blocks).
//  - weight working set 2.36MB stays L2-resident per XCD (no streaming
//    competition: input read once, stores nontemporal).
//  - 512 threads / 8 waves, 1 block/CU (LDS-bound) = 2 waves/SIMD.
//  - stores restored to nontemporal (R7 A/B: plain stores +1.3GB WRITE).
// conv3x3(concat[x, onehot_n], w_rpn) == conv3x3(x, w_rpn[:,:256]) + edge bias
// ---------------------------------------------------------------------------

typedef __attribute__((ext_vector_type(8))) short short8;
typedef __attribute__((ext_vector_type(4))) float f32x4;

#define TOT 80997

struct Tab {
    int tilesX[5];
    int blkBase[6];
    int H[5];
    int W5[5];
    int poff[6];
    int cvtBase[6];
};

static __device__ __forceinline__ ushort f2bf(float f) {
    union { float f; unsigned u; } x; x.f = f;
    unsigned r = (x.u + 0x7FFFu + ((x.u >> 16) & 1u)) >> 16;  // RNE
    return (ushort)r;
}
static __device__ __forceinline__ float bf2f(ushort u) {
    union { unsigned u; float f; } x; x.u = ((unsigned)u) << 16;
    return x.f;
}

static __device__ __forceinline__ void gl_lds16(const ushort* g, ushort* l) {
    __builtin_amdgcn_global_load_lds(
        (const __attribute__((address_space(1))) void*)g,
        (__attribute__((address_space(3))) void*)l, 16, 0, 0);
}

// -------- NCHW fp32 -> NHWC bf16 transpose-convert (64-pos x 256-ic tiles) --
__global__ __launch_bounds__(256) void cvtT_kernel(
    const float* __restrict__ f0, const float* __restrict__ f1,
    const float* __restrict__ f2, const float* __restrict__ f3,
    const float* __restrict__ f4, ushort* __restrict__ xn, Tab tab)
{
    __shared__ __align__(16) ushort s[64 * 264];
    const int tid = threadIdx.x;
    int t = blockIdx.x, L = 0;
    while (t >= tab.cvtBase[L + 1]) ++L;
    const int tile = t - tab.cvtBase[L];
    const int HW = tab.H[L] * tab.W5[L];
    const int pos0 = tile * 64;
    const int b = blockIdx.z;
    const float* fs[5] = {f0, f1, f2, f3, f4};
    const float* xp = fs[L] + (size_t)b * 256 * HW;

    const int p = tid & 63;
    const int icr = tid >> 6;
    const int pos = pos0 + p;
    for (int ic4 = 0; ic4 < 256; ic4 += 4) {
        const int ic = ic4 + icr;
        float v = 0.f;
        if (pos < HW) v = xp[(size_t)ic * HW + pos];
        s[p * 264 + ic] = f2bf(v);
    }
    __syncthreads();
    const int seg = tid & 31;
    for (int k = 0; k < 8; ++k) {
        const int pp = (tid >> 5) + k * 8;
        const int gpos = pos0 + pp;
        if (gpos < HW) {
            short8 v = *(const short8*)&s[pp * 264 + seg * 8];
            __builtin_nontemporal_store(v,
                (short8*)(xn + ((size_t)b * TOT + tab.poff[L] + gpos) * 256 + seg * 8));
        }
    }
}

// -------- weight pack: w[oc][ic][ky][kx] fp32 -> pw[tap][oc][ic] bf16 ------
__global__ __launch_bounds__(256) void pack_w_kernel(
    const float* __restrict__ w, ushort* __restrict__ pw, int icfull)
{
    int idx = blockIdx.x * 256 + threadIdx.x;
    if (idx >= 589824) return;
    int ic  = idx & 255;
    int oc  = (idx >> 8) & 255;
    int tap = idx >> 16;
    pw[idx] = f2bf(w[((size_t)oc * icfull + ic) * 9 + tap]);
}

// -------- qy weight pack: wqy[n][ic][tap] fp32 -> pwqy[n][tap][ic] bf16 ----
__global__ __launch_bounds__(256) void pack_qy_kernel(
    const float* __restrict__ wqy, ushort* __restrict__ pwqy)
{
    int idx = blockIdx.x * 256 + threadIdx.x;   // 4*9*256 = 9216
    if (idx >= 9216) return;
    int ic = idx & 255;
    int t  = (idx >> 8) % 9;
    int n  = (idx >> 8) / 9;
    pwqy[idx] = f2bf(wqy[n * 2304 + ic * 9 + t]);
}

// ---- edge-bias table, transposed: btabT[case][oc][n] (float4 per oc) ------
__global__ __launch_bounds__(256) void btabT_kernel(
    const float* __restrict__ w_rpn, float* __restrict__ btabT)
{
    int idx = blockIdx.x * 256 + threadIdx.x;   // 9*256
    if (idx >= 2304) return;
    const int oc = idx & 255;
    const int cs = idx >> 8;
    const int cy = cs / 3, cx = cs % 3;
    float4 o;
    float* op = (float*)&o;
    for (int n = 0; n < 4; ++n) {
        float s = 0.f;
        for (int ky = 0; ky < 3; ++ky) {
            if (cy == 0 && ky == 0) continue;
            if (cy == 2 && ky == 2) continue;
            for (int kx = 0; kx < 3; ++kx) {
                if (cx == 0 && kx == 0) continue;
                if (cx == 2 && kx == 2) continue;
                s += w_rpn[(size_t)oc * 2340 + (256 + n) * 9 + ky * 3 + kx];
            }
        }
        op[n] = s;
    }
    ((float4*)btabT)[cs * 256 + oc] = o;
}

// -------- head weight pack + zero page ------------------------------------
__global__ void pack_head_kernel(const float* __restrict__ w_cls,
                                 const float* __restrict__ w_mean,
                                 float* __restrict__ wcp, float* __restrict__ wmp,
                                 ushort* __restrict__ zpg)
{
    const int oc = threadIdx.x;  // 256
    wcp[oc * 2]     = w_cls[oc];
    wcp[oc * 2 + 1] = w_cls[256 + oc];
    float4 m;
    m.x = w_mean[oc];       m.y = w_mean[256 + oc];
    m.z = w_mean[512 + oc]; m.w = w_mean[768 + oc];
    ((float4*)wmp)[oc] = m;
    if (oc < 32) zpg[oc] = 0;
}

// ------------------- big 3x3 conv: 256 -> 256, bf16 MFMA -------------------
// Block: 16x8 tile, one batch, 512 threads (8 waves: wrow=wave>>2 picks the
// 64-oc group, wcol=wave&3 picks the y-pair). Full-depth input in LDS:
//   core [8c][40u=(10r x 4icb)][16x][16B] = 81,920 B
//   halo [8c][10r][4icb][2side][16B]      = 10,240 B  (at ushort 40960)
//   s_out [128 pos][136 oc-ushort]        = 34,816 B  (at ushort 46080)
// Total 126,976 B static -> 1 block/CU, 2 waves/SIMD.
// Variants (job,ocHalf) loop INSIDE the block over the resident input.
__global__ __launch_bounds__(512, 2) void conv3x3_mfma(
    const ushort* __restrict__ inN,   // NHWC bf16 [b][TOT][256]
    const ushort* __restrict__ pw0, const ushort* __restrict__ pw1,
    const float* __restrict__ bias0, const float* __restrict__ bias1,
    ushort* __restrict__ out0, ushort* __restrict__ out1,
    const ushort* __restrict__ zpg,
    int jobs, int reluFlags, Tab tab)
{
    __shared__ __align__(16) ushort smem[63488];   // 126,976 B
    ushort* s_out = smem + 46080;

    const int tid = threadIdx.x;
    // XCD-aware bijective swizzle (grid % 8 == 0): contiguous logical chunk
    // per XCD -> halo-neighbor tiles share an L2.
    const int nper = (int)(gridDim.x >> 3);
    const int id = ((int)blockIdx.x & 7) * nper + ((int)blockIdx.x >> 3);

    const int bsum = tab.blkBase[5];
    const int bb = (id >= bsum) ? 1 : 0;
    int t = id - bsum * bb;
    int L = 0;
    while (t >= tab.blkBase[L + 1]) ++L;
    const int rel = t - tab.blkBase[L];
    const int tX = tab.tilesX[L];
    const int H = tab.H[L], W = tab.W5[L];
    const int y0 = (rel / tX) * 8;
    const int x0 = (rel % tX) * 16;
    const int poff = tab.poff[L];

    const int lane = tid & 63;
    const int wave = tid >> 6;       // 0..7
    const int lm   = lane & 15;
    const int quad = lane >> 4;
    const int wrow = wave >> 2;      // 0..1 : 64-oc group within the 128 half
    const int wcol = wave & 3;       // 0..3 : y pair

    const size_t inBase = ((size_t)bb * TOT + poff) * 256;

    // ---- stage full-depth input tile (once) via global_load_lds ----
    {
        const int c = wave;          // each wave stages its own ic-chunk
#pragma unroll
        for (int kk = 0; kk < 10; ++kk) {        // row r = kk
            const int ug = kk * 4;               // 4 units (icb=quad) / instr
            const int yi = y0 - 1 + kk;
            const int xi = x0 + lm;
            const ushort* src = zpg;
            if (yi >= 0 && yi < H && xi < W)
                src = inN + inBase + ((size_t)yi * W + xi) * 256 + c * 32 + quad * 8;
            gl_lds16(src, &smem[(c * 40 + ug) * 128]);
        }
    }
    // halo: 640 16B pieces, layout [c][r][icb][side]
    auto haloStage = [&](int pbase) {
        const int p = pbase + lane;
        const int c = p / 80;
        const int rem = p - c * 80;
        const int r = rem >> 3;
        const int icb = (rem >> 1) & 3;
        const int side = rem & 1;
        const int yi = y0 - 1 + r;
        const int xi = side ? (x0 + 16) : (x0 - 1);
        const ushort* src = zpg;
        if (yi >= 0 && yi < H && xi >= 0 && xi < W)
            src = inN + inBase + ((size_t)yi * W + xi) * 256 + c * 32 + icb * 8;
        gl_lds16(src, &smem[40960 + pbase * 8]);
    };
    haloStage(wave * 64);
    if (wave < 2) haloStage(512 + wave * 64);
    __syncthreads();   // drains gl_lds; input is LDS-resident for all variants

    // ---- variants: (job, ocHalf), sequential over the resident input ----
    const int nv = jobs * 2;
#pragma unroll 1
    for (int v = 0; v < nv; ++v) {
        const int job = v >> 1;
        const int och = v & 1;
        const ushort* pwj  = job ? pw1 : pw0;
        const float*  bsj  = job ? bias1 : bias0;
        ushort*       outj = job ? out1 : out0;
        const int relu = (reluFlags >> job) & 1;
        const ushort* pwl = pwj + (size_t)(och * 128 + wrow * 64 + lm) * 256
                            + quad * 8;

        f32x4 acc[4][2];
#pragma unroll
        for (int i = 0; i < 4; ++i) {
            acc[i][0] = (f32x4){0.f, 0.f, 0.f, 0.f};
            acc[i][1] = (f32x4){0.f, 0.f, 0.f, 0.f};
        }

#pragma unroll 2
        for (int c = 0; c < 8; ++c) {
#pragma unroll
            for (int kx = 0; kx < 3; ++kx) {
                short8 bv[4];   // input rows wcol*2 .. wcol*2+3
#pragma unroll
                for (int rr = 0; rr < 4; ++rr) {
                    const int r = wcol * 2 + rr;
                    const int u = r * 4 + quad;
                    const int lmx = lm + kx - 1;
                    int addr = ((c * 40 + u) * 16 + lmx) * 8;
                    if (kx == 0 && lm == 0)
                        addr = 40960 + (c * 80 + r * 8 + quad * 2 + 0) * 8;
                    if (kx == 2 && lm == 15)
                        addr = 40960 + (c * 80 + r * 8 + quad * 2 + 1) * 8;
                    bv[rr] = *(const short8*)&smem[addr];
                }
#pragma unroll
                for (int ky = 0; ky < 3; ++ky) {
                    const ushort* pa = pwl + (ky * 3 + kx) * 65536 + c * 32;
                    short8 av[4];
#pragma unroll
                    for (int i = 0; i < 4; ++i)
                        av[i] = *(const short8*)(pa + i * 4096);
#pragma unroll
                    for (int i = 0; i < 4; ++i)
#pragma unroll
                        for (int j = 0; j < 2; ++j)
                            acc[i][j] = __builtin_amdgcn_mfma_f32_16x16x32_bf16(
                                av[i], bv[j + ky], acc[i][j], 0, 0, 0);
                }
            }
        }

        // ---- epilogue: LDS transpose then nt stores ----
        __syncthreads();   // prior variant's s_out reads complete
#pragma unroll
        for (int i = 0; i < 4; ++i) {
            const int ocl = wrow * 64 + i * 16 + quad * 4;
            const float4 b4 = *(const float4*)(bsj + och * 128 + ocl);
#pragma unroll
            for (int j = 0; j < 2; ++j) {
                const int posL = (wcol * 2 + j) * 16 + lm;
                float v0 = acc[i][j][0] + b4.x;
                float v1 = acc[i][j][1] + b4.y;
                float v2 = acc[i][j][2] + b4.z;
                float v3 = acc[i][j][3] + b4.w;
                if (relu) {
                    v0 = fmaxf(v0, 0.f); v1 = fmaxf(v1, 0.f);
                    v2 = fmaxf(v2, 0.f); v3 = fmaxf(v3, 0.f);
                }
                ushort4 o;
                o.x = f2bf(v0); o.y = f2bf(v1); o.z = f2bf(v2); o.w = f2bf(v3);
                *(ushort4*)&s_out[posL * 136 + ocl] = o;
            }
        }
        __syncthreads();
        // stores overlap next variant's MFMA loop (nt, fire-and-forget)
#pragma unroll
        for (int it = 0; it < 4; ++it) {
            const int idx = it * 512 + tid;
            const int p   = idx >> 4;
            const int sgm = idx & 15;
            const int y = y0 + (p >> 4), x = x0 + (p & 15);
            if (y < H && x < W) {
                short8 w = *(const short8*)&s_out[p * 136 + sgm * 8];
                __builtin_nontemporal_store(w,
                    (short8*)(outj + ((size_t)bb * TOT + poff + (size_t)y * W + x) * 256
                              + och * 128 + sgm * 8));
            }
        }
    }
}

// ------- qy conv (256->4, 3x3) + softmax; NHWC h2; 4 lanes per position ----
__global__ __launch_bounds__(256) void qy_softmax_kernel(
    const ushort* __restrict__ h2, const ushort* __restrict__ pwqy, // [4][9][256]
    const float* __restrict__ bqy, float* __restrict__ mixv, Tab tab)
{
    const int tid = threadIdx.x;
    const int p = blockIdx.x * 64 + (tid >> 2);
    if (p >= TOT) return;
    const int q = tid & 3;
    const int b = blockIdx.z;
    int L = 0; while (p >= tab.poff[L + 1]) ++L;
    const int pos = p - tab.poff[L];
    const int W = tab.W5[L], H = tab.H[L];
    const int y = pos / W, x = pos - y * W;

    int  off[9];
    bool val[9];
#pragma unroll
    for (int ky = 0; ky < 3; ++ky)
#pragma unroll
        for (int kx = 0; kx < 3; ++kx) {
            const int t = ky * 3 + kx;
            const int yi = y + ky - 1, xi = x + kx - 1;
            val[t] = (yi >= 0 && yi < H && xi >= 0 && xi < W);
            off[t] = ((ky - 1) * W + (kx - 1)) * 256;
        }

    float a0 = 0.f, a1 = 0.f, a2 = 0.f, a3 = 0.f;
    const ushort* hp = h2 + ((size_t)b * TOT + p) * 256;
#pragma unroll 1
    for (int k = 0; k < 8; ++k) {
        const int sb = (k * 4 + q) * 8;
#pragma unroll
        for (int t = 0; t < 9; ++t) {
            if (!val[t]) continue;
            const short8 h8 = *(const short8*)(hp + off[t] + sb);
            float hv[8];
#pragma unroll
            for (int e = 0; e < 8; ++e) hv[e] = bf2f((ushort)h8[e]);
            const short8 w0 = *(const short8*)(pwqy + (0 * 9 + t) * 256 + sb);
            const short8 w1 = *(const short8*)(pwqy + (1 * 9 + t) * 256 + sb);
            const short8 w2 = *(const short8*)(pwqy + (2 * 9 + t) * 256 + sb);
            const short8 w3 = *(const short8*)(pwqy + (3 * 9 + t) * 256 + sb);
#pragma unroll
            for (int e = 0; e < 8; ++e) {
                a0 = fmaf(bf2f((ushort)w0[e]), hv[e], a0);
                a1 = fmaf(bf2f((ushort)w1[e]), hv[e], a1);
                a2 = fmaf(bf2f((ushort)w2[e]), hv[e], a2);
                a3 = fmaf(bf2f((ushort)w3[e]), hv[e], a3);
            }
        }
    }
    a0 += __shfl_xor(a0, 1); a0 += __shfl_xor(a0, 2);
    a1 += __shfl_xor(a1, 1); a1 += __shfl_xor(a1, 2);
    a2 += __shfl_xor(a2, 1); a2 += __shfl_xor(a2, 2);
    a3 += __shfl_xor(a3, 1); a3 += __shfl_xor(a3, 2);
    if (q == 0) {
        a0 += bqy[0]; a1 += bqy[1]; a2 += bqy[2]; a3 += bqy[3];
        const float mx = fmaxf(fmaxf(a0, a1), fmaxf(a2, a3));
        const float e0 = expf(a0 - mx), e1 = expf(a1 - mx);
        const float e2 = expf(a2 - mx), e3 = expf(a3 - mx);
        const float s = 1.f / (e0 + e1 + e2 + e3);
        float4 o; o.x = e0 * s; o.y = e1 * s; o.z = e2 * s; o.w = e3 * s;
        ((float4*)mixv)[(size_t)b * TOT + p] = o;
    }
}

// ------ final: T = sum_n mix_n*relu(u+bias_n); 6 heads; decode; clip -------
__global__ __launch_bounds__(256) void final_kernel(
    const float* __restrict__ mixv, const ushort* __restrict__ U,
    const float* __restrict__ btabT,
    const float* __restrict__ wcp, const float* __restrict__ wmp,
    const float* __restrict__ b_cls, const float* __restrict__ b_mean,
    const float* __restrict__ im_info,
    float* __restrict__ outp, Tab tab)
{
    const int tid = threadIdx.x;
    const int p = blockIdx.x * 64 + (tid >> 2);
    if (p >= TOT) return;
    const int q = tid & 3;
    const int b = blockIdx.z;
    int L = 0; while (p >= tab.poff[L + 1]) ++L;
    const int pos = p - tab.poff[L];
    const int W = tab.W5[L], H = tab.H[L];
    const int y = pos / W, x = pos - y * W;
    const int cy = (y == 0) ? 0 : ((y == H - 1) ? 2 : 1);
    const int cx = (x == 0) ? 0 : ((x == W - 1) ? 2 : 1);
    const float* bT = btabT + (size_t)(cy * 3 + cx) * 1024;

    const float4 mm = ((const float4*)mixv)[(size_t)b * TOT + p];
    const ushort* up = U + ((size_t)b * TOT + p) * 256;

    float sc0 = 0.f, sc1 = 0.f, D0 = 0.f, D1 = 0.f, D2 = 0.f, D3 = 0.f;
#pragma unroll 1
    for (int k = 0; k < 8; ++k) {
        const int seg = k * 4 + q;
        const short8 u8 = *(const short8*)(up + seg * 8);
#pragma unroll
        for (int e = 0; e < 8; ++e) {
            const int oc = seg * 8 + e;
            const float u = bf2f((ushort)u8[e]);
            const float4 bt = *(const float4*)(bT + oc * 4);
            float T =      mm.x * fmaxf(u + bt.x, 0.f);
            T = fmaf(mm.y, fmaxf(u + bt.y, 0.f), T);
            T = fmaf(mm.z, fmaxf(u + bt.z, 0.f), T);
            T = fmaf(mm.w, fmaxf(u + bt.w, 0.f), T);
            const float2 wc = *(const float2*)(wcp + oc * 2);
            const float4 wm = *(const float4*)(wmp + oc * 4);
            sc0 = fmaf(wc.x, T, sc0); sc1 = fmaf(wc.y, T, sc1);
            D0 = fmaf(wm.x, T, D0);   D1 = fmaf(wm.y, T, D1);
            D2 = fmaf(wm.z, T, D2);   D3 = fmaf(wm.w, T, D3);
        }
    }
    sc0 += __shfl_xor(sc0, 1); sc0 += __shfl_xor(sc0, 2);
    sc1 += __shfl_xor(sc1, 1); sc1 += __shfl_xor(sc1, 2);
    D0  += __shfl_xor(D0, 1);  D0  += __shfl_xor(D0, 2);
    D1  += __shfl_xor(D1, 1);  D1  += __shfl_xor(D1, 2);
    D2  += __shfl_xor(D2, 1);  D2  += __shfl_xor(D2, 2);
    D3  += __shfl_xor(D3, 1);  D3  += __shfl_xor(D3, 2);

    if (q == 0) {
        sc0 += b_cls[0]; sc1 += b_cls[1];
        D0 += b_mean[0]; D1 += b_mean[1]; D2 += b_mean[2]; D3 += b_mean[3];
        const float stride_ = (float)(64 >> L);
        const float aw  = stride_ * 8.f;
        const float acx = (x + 0.5f) * stride_;
        const float acy = (y + 0.5f) * stride_;
        const float cxx = acx + D0 * aw;
        const float cyy = acy + D1 * aw;
        const float e2 = fminf(fmaxf(D2, -10.f), 10.f);
        const float e3 = fminf(fmaxf(D3, -10.f), 10.f);
        const float bw = aw * expf(e2);
        const float bh = aw * expf(e3);
        const float imH = im_info[b * 6 + 0], imW = im_info[b * 6 + 1];
        const float x1 = fminf(fmaxf(cxx - 0.5f * bw, 0.f), imW);
        const float y1 = fminf(fmaxf(cyy - 0.5f * bh, 0.f), imH);
        const float x2 = fminf(fmaxf(cxx + 0.5f * bw, 0.f), imW);
        const float y2 = fminf(fmaxf(cyy + 0.5f * bh, 0.f), imH);
        float* op = outp + ((size_t)b * TOT + p) * 6;
        float2 w01; w01.x = x1; w01.y = y1;
        float2 w23; w23.x = x2; w23.y = y2;
        float2 w45; w45.x = sc0; w45.y = sc1;
        ((float2*)op)[0] = w01; ((float2*)op)[1] = w23; ((float2*)op)[2] = w45;
    }
}

// ---------------------------------------------------------------------------
extern "C" void kernel_launch(void* const* d_in, const int* in_sizes, int n_in,
                              void* d_out, int out_size, void* d_ws, size_t ws_size,
                              hipStream_t stream)
{
    (void)in_sizes; (void)n_in; (void)out_size; (void)ws_size;

    const float* im_info = (const float*)d_in[5];
    const float* w_qy1 = (const float*)d_in[6];
    const float* b_qy1 = (const float*)d_in[7];
    const float* w_qy2 = (const float*)d_in[8];
    const float* b_qy2 = (const float*)d_in[9];
    const float* w_qy  = (const float*)d_in[10];
    const float* b_qy  = (const float*)d_in[11];
    const float* w_rpn = (const float*)d_in[12];
    const float* b_rpn = (const float*)d_in[13];
    const float* w_cls = (const float*)d_in[14];
    const float* b_cls = (const float*)d_in[15];
    const float* w_mean= (const float*)d_in[16];
    const float* b_mean= (const float*)d_in[17];
    float* out = (float*)d_out;

    // ---- level tables ----
    Tab tab;
    const int Hs[5]  = {13, 25, 50, 100, 200};
    const int Ws5[5] = {19, 38, 76, 152, 304};
    int bsum = 0, psum = 0, csum = 0;
    for (int L = 0; L < 5; ++L) {
        tab.H[L] = Hs[L]; tab.W5[L] = Ws5[L];
        tab.tilesX[L] = (Ws5[L] + 15) / 16;
        tab.blkBase[L] = bsum;
        bsum += tab.tilesX[L] * ((Hs[L] + 7) / 8);
        tab.poff[L] = psum;
        tab.cvtBase[L] = csum;
        const int HW = Hs[L] * Ws5[L];
        psum += HW;
        csum += (HW + 63) / 64;
    }
    tab.blkBase[5] = bsum; tab.poff[5] = psum; tab.cvtBase[5] = csum;

    // ---- workspace layout (all 16B-aligned) ----
    const size_t BIGE = (size_t)2 * TOT * 256;   // 41,470,464 elems
    ushort* XBF  = (ushort*)d_ws;                // x NHWC; later aliased by H2
    ushort* H1   = XBF + BIGE;                   // h1 NHWC
    ushort* U    = H1 + BIGE;                    // U NHWC
    ushort* H2   = XBF;                          // h2 NHWC, aliases dead XN
    float*  MIXv = (float*)(U + BIGE);           // [b][TOT][4]
    float*  btabT= MIXv + (size_t)2 * TOT * 4;   // 9216
    float*  wcp  = btabT + 9216;                 // 512
    float*  wmp  = wcp + 512;                    // 1024
    ushort* PW1  = (ushort*)(wmp + 1024);
    ushort* PW2  = PW1 + 589824;
    ushort* PWR  = PW2 + 589824;
    ushort* PWQY = PWR + 589824;
    ushort* ZPG  = PWQY + 9216;                  // 32 ushort zero page

    // ---- prep ----
    cvtT_kernel<<<dim3(csum, 1, 2), 256, 0, stream>>>(
        (const float*)d_in[0], (const float*)d_in[1], (const float*)d_in[2],
        (const float*)d_in[3], (const float*)d_in[4], XBF, tab);
    pack_w_kernel<<<2304, 256, 0, stream>>>(w_qy1, PW1, 256);
    pack_w_kernel<<<2304, 256, 0, stream>>>(w_qy2, PW2, 256);
    pack_w_kernel<<<2304, 256, 0, stream>>>(w_rpn, PWR, 260);
    pack_qy_kernel<<<36, 256, 0, stream>>>(w_qy, PWQY);
    btabT_kernel<<<9, 256, 0, stream>>>(w_rpn, btabT);
    pack_head_kernel<<<1, 256, 0, stream>>>(w_cls, w_mean, wcp, wmp, ZPG);

    // ---- D1: conv1 (x->h1, relu) + convR (x->U); variants inside block ----
    conv3x3_mfma<<<dim3(bsum * 2, 1, 1), 512, 0, stream>>>(
        XBF, PW1, PWR, b_qy1, b_rpn, H1, U, ZPG, /*jobs=*/2, /*reluFlags=*/0b01, tab);

    // ---- D2: conv2 (h1->h2, relu); variants inside block ----
    conv3x3_mfma<<<dim3(bsum * 2, 1, 1), 512, 0, stream>>>(
        H1, PW2, PW2, b_qy2, b_qy2, H2, H2, ZPG, /*jobs=*/1, /*reluFlags=*/0b1, tab);

    // ---- D3: qy conv + softmax -> mix ----
    qy_softmax_kernel<<<dim3((TOT + 63) / 64, 1, 2), 256, 0, stream>>>(
        H2, PWQY, b_qy, MIXv, tab);

    // ---- D4: heads + mixture + decode + clip ----
    final_kernel<<<dim3((TOT + 63) / 64, 1, 2), 256, 0, stream>>>(
        MIXv, U, btabT, wcp, wmp, b_cls, b_mean, im_info, out, tab);
}

// Round 3
// 2139.505 us; speedup vs baseline: 1.4064x; 1.4064x over previous
//
#include <hip/hip_runtime.h>
#include <math.h>

// ---------------------------------------------------------------------------
// RPN GMM head, MI355X. Round 9: wave-contiguous weight layout.
// R8 post-mortem: traffic solved (FETCH 86MB, WRITE 162MB = hand counts) but
// MfmaUtil 9.8% / VALUBusy 5.8% -> transaction-rate bound: old pw layout made
// each A-fragment wave-load touch 64 distinct cache lines (16B used per 64B).
// Fix: pack pw as [tap][c][ocg][lm][quad][8ic] so each av[i] instruction reads
// one contiguous 1KB block (16 fully-used lines); the 4 wcol-waves re-read the
// same 12KB/(c,kx) stream -> L1-resident. Everything else unchanged from R8.
// conv3x3(concat[x, onehot_n], w_rpn) == conv3x3(x, w_rpn[:,:256]) + edge bias
// ---------------------------------------------------------------------------

typedef __attribute__((ext_vector_type(8))) short short8;
typedef __attribute__((ext_vector_type(4))) float f32x4;

#define TOT 80997

struct Tab {
    int tilesX[5];
    int blkBase[6];
    int H[5];
    int W5[5];
    int poff[6];
    int cvtBase[6];
};

static __device__ __forceinline__ ushort f2bf(float f) {
    union { float f; unsigned u; } x; x.f = f;
    unsigned r = (x.u + 0x7FFFu + ((x.u >> 16) & 1u)) >> 16;  // RNE
    return (ushort)r;
}
static __device__ __forceinline__ float bf2f(ushort u) {
    union { unsigned u; float f; } x; x.u = ((unsigned)u) << 16;
    return x.f;
}

static __device__ __forceinline__ void gl_lds16(const ushort* g, ushort* l) {
    __builtin_amdgcn_global_load_lds(
        (const __attribute__((address_space(1))) void*)g,
        (__attribute__((address_space(3))) void*)l, 16, 0, 0);
}

// -------- NCHW fp32 -> NHWC bf16 transpose-convert (64-pos x 256-ic tiles) --
__global__ __launch_bounds__(256) void cvtT_kernel(
    const float* __restrict__ f0, const float* __restrict__ f1,
    const float* __restrict__ f2, const float* __restrict__ f3,
    const float* __restrict__ f4, ushort* __restrict__ xn, Tab tab)
{
    __shared__ __align__(16) ushort s[64 * 264];
    const int tid = threadIdx.x;
    int t = blockIdx.x, L = 0;
    while (t >= tab.cvtBase[L + 1]) ++L;
    const int tile = t - tab.cvtBase[L];
    const int HW = tab.H[L] * tab.W5[L];
    const int pos0 = tile * 64;
    const int b = blockIdx.z;
    const float* fs[5] = {f0, f1, f2, f3, f4};
    const float* xp = fs[L] + (size_t)b * 256 * HW;

    const int p = tid & 63;
    const int icr = tid >> 6;
    const int pos = pos0 + p;
    for (int ic4 = 0; ic4 < 256; ic4 += 4) {
        const int ic = ic4 + icr;
        float v = 0.f;
        if (pos < HW) v = xp[(size_t)ic * HW + pos];
        s[p * 264 + ic] = f2bf(v);
    }
    __syncthreads();
    const int seg = tid & 31;
    for (int k = 0; k < 8; ++k) {
        const int pp = (tid >> 5) + k * 8;
        const int gpos = pos0 + pp;
        if (gpos < HW) {
            short8 v = *(const short8*)&s[pp * 264 + seg * 8];
            __builtin_nontemporal_store(v,
                (short8*)(xn + ((size_t)b * TOT + tab.poff[L] + gpos) * 256 + seg * 8));
        }
    }
}

// ---- weight pack: w[oc][ic][tap] fp32 -> pw[tap][c8][ocg16][lm16][q4][8] --
// idx = ((tap*8 + c)*16 + ocg)*512 + lm*32 + qe ; oc = ocg*16+lm, ic = c*32+qe
__global__ __launch_bounds__(256) void pack_w_kernel(
    const float* __restrict__ w, ushort* __restrict__ pw, int icfull)
{
    int idx = blockIdx.x * 256 + threadIdx.x;
    if (idx >= 589824) return;
    const int within = idx & 511;
    const int lm  = within >> 5;
    const int qe  = within & 31;
    const int rest = idx >> 9;
    const int ocg = rest & 15;
    const int tc  = rest >> 4;
    const int c   = tc & 7;
    const int tap = tc >> 3;
    const int oc = ocg * 16 + lm;
    const int ic = c * 32 + qe;
    pw[idx] = f2bf(w[((size_t)oc * icfull + ic) * 9 + tap]);
}

// -------- qy weight pack: wqy[n][ic][tap] fp32 -> pwqy[n][tap][ic] bf16 ----
__global__ __launch_bounds__(256) void pack_qy_kernel(
    const float* __restrict__ wqy, ushort* __restrict__ pwqy)
{
    int idx = blockIdx.x * 256 + threadIdx.x;   // 4*9*256 = 9216
    if (idx >= 9216) return;
    int ic = idx & 255;
    int t  = (idx >> 8) % 9;
    int n  = (idx >> 8) / 9;
    pwqy[idx] = f2bf(wqy[n * 2304 + ic * 9 + t]);
}

// ---- edge-bias table, transposed: btabT[case][oc][n] (float4 per oc) ------
__global__ __launch_bounds__(256) void btabT_kernel(
    const float* __restrict__ w_rpn, float* __restrict__ btabT)
{
    int idx = blockIdx.x * 256 + threadIdx.x;   // 9*256
    if (idx >= 2304) return;
    const int oc = idx & 255;
    const int cs = idx >> 8;
    const int cy = cs / 3, cx = cs % 3;
    float4 o;
    float* op = (float*)&o;
    for (int n = 0; n < 4; ++n) {
        float s = 0.f;
        for (int ky = 0; ky < 3; ++ky) {
            if (cy == 0 && ky == 0) continue;
            if (cy == 2 && ky == 2) continue;
            for (int kx = 0; kx < 3; ++kx) {
                if (cx == 0 && kx == 0) continue;
                if (cx == 2 && kx == 2) continue;
                s += w_rpn[(size_t)oc * 2340 + (256 + n) * 9 + ky * 3 + kx];
            }
        }
        op[n] = s;
    }
    ((float4*)btabT)[cs * 256 + oc] = o;
}

// -------- head weight pack + zero page ------------------------------------
__global__ void pack_head_kernel(const float* __restrict__ w_cls,
                                 const float* __restrict__ w_mean,
                                 float* __restrict__ wcp, float* __restrict__ wmp,
                                 ushort* __restrict__ zpg)
{
    const int oc = threadIdx.x;  // 256
    wcp[oc * 2]     = w_cls[oc];
    wcp[oc * 2 + 1] = w_cls[256 + oc];
    float4 m;
    m.x = w_mean[oc];       m.y = w_mean[256 + oc];
    m.z = w_mean[512 + oc]; m.w = w_mean[768 + oc];
    ((float4*)wmp)[oc] = m;
    if (oc < 32) zpg[oc] = 0;
}

// ------------------- big 3x3 conv: 256 -> 256, bf16 MFMA -------------------
// Block: 16x8 tile, one batch, 512 threads (8 waves: wrow=wave>>2 picks the
// 64-oc group, wcol=wave&3 picks the y-pair). Full-depth input in LDS:
//   core [8c][40u=(10r x 4icb)][16x][16B] = 81,920 B
//   halo [8c][10r][4icb][2side][16B]      = 10,240 B  (at ushort 40960)
//   s_out [128 pos][136 oc-ushort]        = 34,816 B  (at ushort 46080)
// Total 126,976 B static -> 1 block/CU, 2 waves/SIMD.
// Variants (job,ocHalf) loop INSIDE the block over the resident input.
__global__ __launch_bounds__(512, 2) void conv3x3_mfma(
    const ushort* __restrict__ inN,   // NHWC bf16 [b][TOT][256]
    const ushort* __restrict__ pw0, const ushort* __restrict__ pw1,
    const float* __restrict__ bias0, const float* __restrict__ bias1,
    ushort* __restrict__ out0, ushort* __restrict__ out1,
    const ushort* __restrict__ zpg,
    int jobs, int reluFlags, Tab tab)
{
    __shared__ __align__(16) ushort smem[63488];   // 126,976 B
    ushort* s_out = smem + 46080;

    const int tid = threadIdx.x;
    // XCD-aware bijective swizzle (grid % 8 == 0): contiguous logical chunk
    // per XCD -> halo-neighbor tiles share an L2.
    const int nper = (int)(gridDim.x >> 3);
    const int id = ((int)blockIdx.x & 7) * nper + ((int)blockIdx.x >> 3);

    const int bsum = tab.blkBase[5];
    const int bb = (id >= bsum) ? 1 : 0;
    int t = id - bsum * bb;
    int L = 0;
    while (t >= tab.blkBase[L + 1]) ++L;
    const int rel = t - tab.blkBase[L];
    const int tX = tab.tilesX[L];
    const int H = tab.H[L], W = tab.W5[L];
    const int y0 = (rel / tX) * 8;
    const int x0 = (rel % tX) * 16;
    const int poff = tab.poff[L];

    const int lane = tid & 63;
    const int wave = tid >> 6;       // 0..7
    const int lm   = lane & 15;
    const int quad = lane >> 4;
    const int wrow = wave >> 2;      // 0..1 : 64-oc group within the 128 half
    const int wcol = wave & 3;       // 0..3 : y pair

    const size_t inBase = ((size_t)bb * TOT + poff) * 256;

    // ---- stage full-depth input tile (once) via global_load_lds ----
    {
        const int c = wave;          // each wave stages its own ic-chunk
#pragma unroll
        for (int kk = 0; kk < 10; ++kk) {        // row r = kk
            const int ug = kk * 4;               // 4 units (icb=quad) / instr
            const int yi = y0 - 1 + kk;
            const int xi = x0 + lm;
            const ushort* src = zpg;
            if (yi >= 0 && yi < H && xi < W)
                src = inN + inBase + ((size_t)yi * W + xi) * 256 + c * 32 + quad * 8;
            gl_lds16(src, &smem[(c * 40 + ug) * 128]);
        }
    }
    // halo: 640 16B pieces, layout [c][r][icb][side]
    auto haloStage = [&](int pbase) {
        const int p = pbase + lane;
        const int c = p / 80;
        const int rem = p - c * 80;
        const int r = rem >> 3;
        const int icb = (rem >> 1) & 3;
        const int side = rem & 1;
        const int yi = y0 - 1 + r;
        const int xi = side ? (x0 + 16) : (x0 - 1);
        const ushort* src = zpg;
        if (yi >= 0 && yi < H && xi >= 0 && xi < W)
            src = inN + inBase + ((size_t)yi * W + xi) * 256 + c * 32 + icb * 8;
        gl_lds16(src, &smem[40960 + pbase * 8]);
    };
    haloStage(wave * 64);
    if (wave < 2) haloStage(512 + wave * 64);
    __syncthreads();   // drains gl_lds; input is LDS-resident for all variants

    // ---- variants: (job, ocHalf), sequential over the resident input ----
    const int nv = jobs * 2;
#pragma unroll 1
    for (int v = 0; v < nv; ++v) {
        const int job = v >> 1;
        const int och = v & 1;
        const ushort* pwj  = job ? pw1 : pw0;
        const float*  bsj  = job ? bias1 : bias0;
        ushort*       outj = job ? out1 : out0;
        const int relu = (reluFlags >> job) & 1;
        // wave-contiguous layout: block (tap,c,ocg) of 512 ushorts; lane
        // offset lm*32 + quad*8 -> each av[i] load = contiguous 1KB.
        const ushort* pwl = pwj + (size_t)(och * 8 + wrow * 4) * 512
                            + lm * 32 + quad * 8;

        f32x4 acc[4][2];
#pragma unroll
        for (int i = 0; i < 4; ++i) {
            acc[i][0] = (f32x4){0.f, 0.f, 0.f, 0.f};
            acc[i][1] = (f32x4){0.f, 0.f, 0.f, 0.f};
        }

#pragma unroll 2
        for (int c = 0; c < 8; ++c) {
#pragma unroll
            for (int kx = 0; kx < 3; ++kx) {
                short8 bv[4];   // input rows wcol*2 .. wcol*2+3
#pragma unroll
                for (int rr = 0; rr < 4; ++rr) {
                    const int r = wcol * 2 + rr;
                    const int u = r * 4 + quad;
                    const int lmx = lm + kx - 1;
                    int addr = ((c * 40 + u) * 16 + lmx) * 8;
                    if (kx == 0 && lm == 0)
                        addr = 40960 + (c * 80 + r * 8 + quad * 2 + 0) * 8;
                    if (kx == 2 && lm == 15)
                        addr = 40960 + (c * 80 + r * 8 + quad * 2 + 1) * 8;
                    bv[rr] = *(const short8*)&smem[addr];
                }
#pragma unroll
                for (int ky = 0; ky < 3; ++ky) {
                    const ushort* pa = pwl + (size_t)((ky * 3 + kx) * 8 + c) * 8192;
                    short8 av[4];
#pragma unroll
                    for (int i = 0; i < 4; ++i)
                        av[i] = *(const short8*)(pa + i * 512);
#pragma unroll
                    for (int i = 0; i < 4; ++i)
#pragma unroll
                        for (int j = 0; j < 2; ++j)
                            acc[i][j] = __builtin_amdgcn_mfma_f32_16x16x32_bf16(
                                av[i], bv[j + ky], acc[i][j], 0, 0, 0);
                }
            }
        }

        // ---- epilogue: LDS transpose then nt stores ----
        __syncthreads();   // prior variant's s_out reads complete
#pragma unroll
        for (int i = 0; i < 4; ++i) {
            const int ocl = wrow * 64 + i * 16 + quad * 4;
            const float4 b4 = *(const float4*)(bsj + och * 128 + ocl);
#pragma unroll
            for (int j = 0; j < 2; ++j) {
                const int posL = (wcol * 2 + j) * 16 + lm;
                float v0 = acc[i][j][0] + b4.x;
                float v1 = acc[i][j][1] + b4.y;
                float v2 = acc[i][j][2] + b4.z;
                float v3 = acc[i][j][3] + b4.w;
                if (relu) {
                    v0 = fmaxf(v0, 0.f); v1 = fmaxf(v1, 0.f);
                    v2 = fmaxf(v2, 0.f); v3 = fmaxf(v3, 0.f);
                }
                ushort4 o;
                o.x = f2bf(v0); o.y = f2bf(v1); o.z = f2bf(v2); o.w = f2bf(v3);
                *(ushort4*)&s_out[posL * 136 + ocl] = o;
            }
        }
        __syncthreads();
        // stores overlap next variant's MFMA loop (nt, fire-and-forget)
#pragma unroll
        for (int it = 0; it < 4; ++it) {
            const int idx = it * 512 + tid;
            const int p   = idx >> 4;
            const int sgm = idx & 15;
            const int y = y0 + (p >> 4), x = x0 + (p & 15);
            if (y < H && x < W) {
                short8 w = *(const short8*)&s_out[p * 136 + sgm * 8];
                __builtin_nontemporal_store(w,
                    (short8*)(outj + ((size_t)bb * TOT + poff + (size_t)y * W + x) * 256
                              + och * 128 + sgm * 8));
            }
        }
    }
}

// ------- qy conv (256->4, 3x3) + softmax; NHWC h2; 4 lanes per position ----
__global__ __launch_bounds__(256) void qy_softmax_kernel(
    const ushort* __restrict__ h2, const ushort* __restrict__ pwqy, // [4][9][256]
    const float* __restrict__ bqy, float* __restrict__ mixv, Tab tab)
{
    const int tid = threadIdx.x;
    const int p = blockIdx.x * 64 + (tid >> 2);
    if (p >= TOT) return;
    const int q = tid & 3;
    const int b = blockIdx.z;
    int L = 0; while (p >= tab.poff[L + 1]) ++L;
    const int pos = p - tab.poff[L];
    const int W = tab.W5[L], H = tab.H[L];
    const int y = pos / W, x = pos - y * W;

    int  off[9];
    bool val[9];
#pragma unroll
    for (int ky = 0; ky < 3; ++ky)
#pragma unroll
        for (int kx = 0; kx < 3; ++kx) {
            const int t = ky * 3 + kx;
            const int yi = y + ky - 1, xi = x + kx - 1;
            val[t] = (yi >= 0 && yi < H && xi >= 0 && xi < W);
            off[t] = ((ky - 1) * W + (kx - 1)) * 256;
        }

    float a0 = 0.f, a1 = 0.f, a2 = 0.f, a3 = 0.f;
    const ushort* hp = h2 + ((size_t)b * TOT + p) * 256;
#pragma unroll 1
    for (int k = 0; k < 8; ++k) {
        const int sb = (k * 4 + q) * 8;
#pragma unroll
        for (int t = 0; t < 9; ++t) {
            if (!val[t]) continue;
            const short8 h8 = *(const short8*)(hp + off[t] + sb);
            float hv[8];
#pragma unroll
            for (int e = 0; e < 8; ++e) hv[e] = bf2f((ushort)h8[e]);
            const short8 w0 = *(const short8*)(pwqy + (0 * 9 + t) * 256 + sb);
            const short8 w1 = *(const short8*)(pwqy + (1 * 9 + t) * 256 + sb);
            const short8 w2 = *(const short8*)(pwqy + (2 * 9 + t) * 256 + sb);
            const short8 w3 = *(const short8*)(pwqy + (3 * 9 + t) * 256 + sb);
#pragma unroll
            for (int e = 0; e < 8; ++e) {
                a0 = fmaf(bf2f((ushort)w0[e]), hv[e], a0);
                a1 = fmaf(bf2f((ushort)w1[e]), hv[e], a1);
                a2 = fmaf(bf2f((ushort)w2[e]), hv[e], a2);
                a3 = fmaf(bf2f((ushort)w3[e]), hv[e], a3);
            }
        }
    }
    a0 += __shfl_xor(a0, 1); a0 += __shfl_xor(a0, 2);
    a1 += __shfl_xor(a1, 1); a1 += __shfl_xor(a1, 2);
    a2 += __shfl_xor(a2, 1); a2 += __shfl_xor(a2, 2);
    a3 += __shfl_xor(a3, 1); a3 += __shfl_xor(a3, 2);
    if (q == 0) {
        a0 += bqy[0]; a1 += bqy[1]; a2 += bqy[2]; a3 += bqy[3];
        const float mx = fmaxf(fmaxf(a0, a1), fmaxf(a2, a3));
        const float e0 = expf(a0 - mx), e1 = expf(a1 - mx);
        const float e2 = expf(a2 - mx), e3 = expf(a3 - mx);
        const float s = 1.f / (e0 + e1 + e2 + e3);
        float4 o; o.x = e0 * s; o.y = e1 * s; o.z = e2 * s; o.w = e3 * s;
        ((float4*)mixv)[(size_t)b * TOT + p] = o;
    }
}

// ------ final: T = sum_n mix_n*relu(u+bias_n); 6 heads; decode; clip -------
__global__ __launch_bounds__(256) void final_kernel(
    const float* __restrict__ mixv, const ushort* __restrict__ U,
    const float* __restrict__ btabT,
    const float* __restrict__ wcp, const float* __restrict__ wmp,
    const float* __restrict__ b_cls, const float* __restrict__ b_mean,
    const float* __restrict__ im_info,
    float* __restrict__ outp, Tab tab)
{
    const int tid = threadIdx.x;
    const int p = blockIdx.x * 64 + (tid >> 2);
    if (p >= TOT) return;
    const int q = tid & 3;
    const int b = blockIdx.z;
    int L = 0; while (p >= tab.poff[L + 1]) ++L;
    const int pos = p - tab.poff[L];
    const int W = tab.W5[L], H = tab.H[L];
    const int y = pos / W, x = pos - y * W;
    const int cy = (y == 0) ? 0 : ((y == H - 1) ? 2 : 1);
    const int cx = (x == 0) ? 0 : ((x == W - 1) ? 2 : 1);
    const float* bT = btabT + (size_t)(cy * 3 + cx) * 1024;

    const float4 mm = ((const float4*)mixv)[(size_t)b * TOT + p];
    const ushort* up = U + ((size_t)b * TOT + p) * 256;

    float sc0 = 0.f, sc1 = 0.f, D0 = 0.f, D1 = 0.f, D2 = 0.f, D3 = 0.f;
#pragma unroll 1
    for (int k = 0; k < 8; ++k) {
        const int seg = k * 4 + q;
        const short8 u8 = *(const short8*)(up + seg * 8);
#pragma unroll
        for (int e = 0; e < 8; ++e) {
            const int oc = seg * 8 + e;
            const float u = bf2f((ushort)u8[e]);
            const float4 bt = *(const float4*)(bT + oc * 4);
            float T =      mm.x * fmaxf(u + bt.x, 0.f);
            T = fmaf(mm.y, fmaxf(u + bt.y, 0.f), T);
            T = fmaf(mm.z, fmaxf(u + bt.z, 0.f), T);
            T = fmaf(mm.w, fmaxf(u + bt.w, 0.f), T);
            const float2 wc = *(const float2*)(wcp + oc * 2);
            const float4 wm = *(const float4*)(wmp + oc * 4);
            sc0 = fmaf(wc.x, T, sc0); sc1 = fmaf(wc.y, T, sc1);
            D0 = fmaf(wm.x, T, D0);   D1 = fmaf(wm.y, T, D1);
            D2 = fmaf(wm.z, T, D2);   D3 = fmaf(wm.w, T, D3);
        }
    }
    sc0 += __shfl_xor(sc0, 1); sc0 += __shfl_xor(sc0, 2);
    sc1 += __shfl_xor(sc1, 1); sc1 += __shfl_xor(sc1, 2);
    D0  += __shfl_xor(D0, 1);  D0  += __shfl_xor(D0, 2);
    D1  += __shfl_xor(D1, 1);  D1  += __shfl_xor(D1, 2);
    D2  += __shfl_xor(D2, 1);  D2  += __shfl_xor(D2, 2);
    D3  += __shfl_xor(D3, 1);  D3  += __shfl_xor(D3, 2);

    if (q == 0) {
        sc0 += b_cls[0]; sc1 += b_cls[1];
        D0 += b_mean[0]; D1 += b_mean[1]; D2 += b_mean[2]; D3 += b_mean[3];
        const float stride_ = (float)(64 >> L);
        const float aw  = stride_ * 8.f;
        const float acx = (x + 0.5f) * stride_;
        const float acy = (y + 0.5f) * stride_;
        const float cxx = acx + D0 * aw;
        const float cyy = acy + D1 * aw;
        const float e2 = fminf(fmaxf(D2, -10.f), 10.f);
        const float e3 = fminf(fmaxf(D3, -10.f), 10.f);
        const float bw = aw * expf(e2);
        const float bh = aw * expf(e3);
        const float imH = im_info[b * 6 + 0], imW = im_info[b * 6 + 1];
        const float x1 = fminf(fmaxf(cxx - 0.5f * bw, 0.f), imW);
        const float y1 = fminf(fmaxf(cyy - 0.5f * bh, 0.f), imH);
        const float x2 = fminf(fmaxf(cxx + 0.5f * bw, 0.f), imW);
        const float y2 = fminf(fmaxf(cyy + 0.5f * bh, 0.f), imH);
        float* op = outp + ((size_t)b * TOT + p) * 6;
        float2 w01; w01.x = x1; w01.y = y1;
        float2 w23; w23.x = x2; w23.y = y2;
        float2 w45; w45.x = sc0; w45.y = sc1;
        ((float2*)op)[0] = w01; ((float2*)op)[1] = w23; ((float2*)op)[2] = w45;
    }
}

// ---------------------------------------------------------------------------
extern "C" void kernel_launch(void* const* d_in, const int* in_sizes, int n_in,
                              void* d_out, int out_size, void* d_ws, size_t ws_size,
                              hipStream_t stream)
{
    (void)in_sizes; (void)n_in; (void)out_size; (void)ws_size;

    const float* im_info = (const float*)d_in[5];
    const float* w_qy1 = (const float*)d_in[6];
    const float* b_qy1 = (const float*)d_in[7];
    const float* w_qy2 = (const float*)d_in[8];
    const float* b_qy2 = (const float*)d_in[9];
    const float* w_qy  = (const float*)d_in[10];
    const float* b_qy  = (const float*)d_in[11];
    const float* w_rpn = (const float*)d_in[12];
    const float* b_rpn = (const float*)d_in[13];
    const float* w_cls = (const float*)d_in[14];
    const float* b_cls = (const float*)d_in[15];
    const float* w_mean= (const float*)d_in[16];
    const float* b_mean= (const float*)d_in[17];
    float* out = (float*)d_out;

    // ---- level tables ----
    Tab tab;
    const int Hs[5]  = {13, 25, 50, 100, 200};
    const int Ws5[5] = {19, 38, 76, 152, 304};
    int bsum = 0, psum = 0, csum = 0;
    for (int L = 0; L < 5; ++L) {
        tab.H[L] = Hs[L]; tab.W5[L] = Ws5[L];
        tab.tilesX[L] = (Ws5[L] + 15) / 16;
        tab.blkBase[L] = bsum;
        bsum += tab.tilesX[L] * ((Hs[L] + 7) / 8);
        tab.poff[L] = psum;
        tab.cvtBase[L] = csum;
        const int HW = Hs[L] * Ws5[L];
        psum += HW;
        csum += (HW + 63) / 64;
    }
    tab.blkBase[5] = bsum; tab.poff[5] = psum; tab.cvtBase[5] = csum;

    // ---- workspace layout (all 16B-aligned) ----
    const size_t BIGE = (size_t)2 * TOT * 256;   // 41,470,464 elems
    ushort* XBF  = (ushort*)d_ws;                // x NHWC; later aliased by H2
    ushort* H1   = XBF + BIGE;                   // h1 NHWC
    ushort* U    = H1 + BIGE;                    // U NHWC
    ushort* H2   = XBF;                          // h2 NHWC, aliases dead XN
    float*  MIXv = (float*)(U + BIGE);           // [b][TOT][4]
    float*  btabT= MIXv + (size_t)2 * TOT * 4;   // 9216
    float*  wcp  = btabT + 9216;                 // 512
    float*  wmp  = wcp + 512;                    // 1024
    ushort* PW1  = (ushort*)(wmp + 1024);
    ushort* PW2  = PW1 + 589824;
    ushort* PWR  = PW2 + 589824;
    ushort* PWQY = PWR + 589824;
    ushort* ZPG  = PWQY + 9216;                  // 32 ushort zero page

    // ---- prep ----
    cvtT_kernel<<<dim3(csum, 1, 2), 256, 0, stream>>>(
        (const float*)d_in[0], (const float*)d_in[1], (const float*)d_in[2],
        (const float*)d_in[3], (const float*)d_in[4], XBF, tab);
    pack_w_kernel<<<2304, 256, 0, stream>>>(w_qy1, PW1, 256);
    pack_w_kernel<<<2304, 256, 0, stream>>>(w_qy2, PW2, 256);
    pack_w_kernel<<<2304, 256, 0, stream>>>(w_rpn, PWR, 260);
    pack_qy_kernel<<<36, 256, 0, stream>>>(w_qy, PWQY);
    btabT_kernel<<<9, 256, 0, stream>>>(w_rpn, btabT);
    pack_head_kernel<<<1, 256, 0, stream>>>(w_cls, w_mean, wcp, wmp, ZPG);

    // ---- D1: conv1 (x->h1, relu) + convR (x->U); variants inside block ----
    conv3x3_mfma<<<dim3(bsum * 2, 1, 1), 512, 0, stream>>>(
        XBF, PW1, PWR, b_qy1, b_rpn, H1, U, ZPG, /*jobs=*/2, /*reluFlags=*/0b01, tab);

    // ---- D2: conv2 (h1->h2, relu); variants inside block ----
    conv3x3_mfma<<<dim3(bsum * 2, 1, 1), 512, 0, stream>>>(
        H1, PW2, PW2, b_qy2, b_qy2, H2, H2, ZPG, /*jobs=*/1, /*reluFlags=*/0b1, tab);

    // ---- D3: qy conv + softmax -> mix ----
    qy_softmax_kernel<<<dim3((TOT + 63) / 64, 1, 2), 256, 0, stream>>>(
        H2, PWQY, b_qy, MIXv, tab);

    // ---- D4: heads + mixture + decode + clip ----
    final_kernel<<<dim3((TOT + 63) / 64, 1, 2), 256, 0, stream>>>(
        MIXv, U, btabT, wcp, wmp, b_cls, b_mean, im_info, out, tab);
}

// Round 5
// 1374.689 us; speedup vs baseline: 2.1889x; 1.5564x over previous
//
#include <hip/hip_runtime.h>
#include <math.h>

// ---------------------------------------------------------------------------
// RPN GMM head, MI355X. Round 10 (resubmit; R4 was an infra failure).
// oc-partitioned waves (dedup weight streams).
// R9 post-mortem: traffic minimal (86MB/162MB) but MfmaUtil 15% — per-CU VMEM
// bytes/block were 9.4MB because the 4 wcol-waves of each wrow group streamed
// IDENTICAL weight fragments (4x duplication) at ~19B/cyc/CU = the wall.
// Fix: each wave owns a distinct 32-oc slice (i=2 frags) x all 8 y-rows
// (j=8 frags, acc=64 AGPR, fits: VGPR budget 256 at 2 waves/SIMD). Weight
// streams are now disjoint: per-CU weight bytes/block 9.4MB -> 2.36MB (4x).
// Epilogue: block produces all 256 oc/position -> 2 position-halves through
// 33.8KB s_out; stores 512B-contiguous. LDS 126KB, 1 block/CU unchanged.
// conv3x3(concat[x, onehot_n], w_rpn) == conv3x3(x, w_rpn[:,:256]) + edge bias
// ---------------------------------------------------------------------------

typedef __attribute__((ext_vector_type(8))) short short8;
typedef __attribute__((ext_vector_type(4))) float f32x4;

#define TOT 80997

struct Tab {
    int tilesX[5];
    int blkBase[6];
    int H[5];
    int W5[5];
    int poff[6];
    int cvtBase[6];
};

static __device__ __forceinline__ ushort f2bf(float f) {
    union { float f; unsigned u; } x; x.f = f;
    unsigned r = (x.u + 0x7FFFu + ((x.u >> 16) & 1u)) >> 16;  // RNE
    return (ushort)r;
}
static __device__ __forceinline__ float bf2f(ushort u) {
    union { unsigned u; float f; } x; x.u = ((unsigned)u) << 16;
    return x.f;
}

static __device__ __forceinline__ void gl_lds16(const ushort* g, ushort* l) {
    __builtin_amdgcn_global_load_lds(
        (const __attribute__((address_space(1))) void*)g,
        (__attribute__((address_space(3))) void*)l, 16, 0, 0);
}

// -------- NCHW fp32 -> NHWC bf16 transpose-convert (64-pos x 256-ic tiles) --
__global__ __launch_bounds__(256) void cvtT_kernel(
    const float* __restrict__ f0, const float* __restrict__ f1,
    const float* __restrict__ f2, const float* __restrict__ f3,
    const float* __restrict__ f4, ushort* __restrict__ xn, Tab tab)
{
    __shared__ __align__(16) ushort s[64 * 264];
    const int tid = threadIdx.x;
    int t = blockIdx.x, L = 0;
    while (t >= tab.cvtBase[L + 1]) ++L;
    const int tile = t - tab.cvtBase[L];
    const int HW = tab.H[L] * tab.W5[L];
    const int pos0 = tile * 64;
    const int b = blockIdx.z;
    const float* fs[5] = {f0, f1, f2, f3, f4};
    const float* xp = fs[L] + (size_t)b * 256 * HW;

    const int p = tid & 63;
    const int icr = tid >> 6;
    const int pos = pos0 + p;
    for (int ic4 = 0; ic4 < 256; ic4 += 4) {
        const int ic = ic4 + icr;
        float v = 0.f;
        if (pos < HW) v = xp[(size_t)ic * HW + pos];
        s[p * 264 + ic] = f2bf(v);
    }
    __syncthreads();
    const int seg = tid & 31;
    for (int k = 0; k < 8; ++k) {
        const int pp = (tid >> 5) + k * 8;
        const int gpos = pos0 + pp;
        if (gpos < HW) {
            short8 v = *(const short8*)&s[pp * 264 + seg * 8];
            __builtin_nontemporal_store(v,
                (short8*)(xn + ((size_t)b * TOT + tab.poff[L] + gpos) * 256 + seg * 8));
        }
    }
}

// ---- weight pack: w[oc][ic][tap] fp32 -> pw[tap][c8][ocg16][lm16][q4][8] --
// idx = ((tap*8 + c)*16 + ocg)*512 + lm*32 + qe ; oc = ocg*16+lm, ic = c*32+qe
__global__ __launch_bounds__(256) void pack_w_kernel(
    const float* __restrict__ w, ushort* __restrict__ pw, int icfull)
{
    int idx = blockIdx.x * 256 + threadIdx.x;
    if (idx >= 589824) return;
    const int within = idx & 511;
    const int lm  = within >> 5;
    const int qe  = within & 31;
    const int rest = idx >> 9;
    const int ocg = rest & 15;
    const int tc  = rest >> 4;
    const int c   = tc & 7;
    const int tap = tc >> 3;
    const int oc = ocg * 16 + lm;
    const int ic = c * 32 + qe;
    pw[idx] = f2bf(w[((size_t)oc * icfull + ic) * 9 + tap]);
}

// -------- qy weight pack: wqy[n][ic][tap] fp32 -> pwqy[n][tap][ic] bf16 ----
__global__ __launch_bounds__(256) void pack_qy_kernel(
    const float* __restrict__ wqy, ushort* __restrict__ pwqy)
{
    int idx = blockIdx.x * 256 + threadIdx.x;   // 4*9*256 = 9216
    if (idx >= 9216) return;
    int ic = idx & 255;
    int t  = (idx >> 8) % 9;
    int n  = (idx >> 8) / 9;
    pwqy[idx] = f2bf(wqy[n * 2304 + ic * 9 + t]);
}

// ---- edge-bias table, transposed: btabT[case][oc][n] (float4 per oc) ------
__global__ __launch_bounds__(256) void btabT_kernel(
    const float* __restrict__ w_rpn, float* __restrict__ btabT)
{
    int idx = blockIdx.x * 256 + threadIdx.x;   // 9*256
    if (idx >= 2304) return;
    const int oc = idx & 255;
    const int cs = idx >> 8;
    const int cy = cs / 3, cx = cs % 3;
    float4 o;
    float* op = (float*)&o;
    for (int n = 0; n < 4; ++n) {
        float s = 0.f;
        for (int ky = 0; ky < 3; ++ky) {
            if (cy == 0 && ky == 0) continue;
            if (cy == 2 && ky == 2) continue;
            for (int kx = 0; kx < 3; ++kx) {
                if (cx == 0 && kx == 0) continue;
                if (cx == 2 && kx == 2) continue;
                s += w_rpn[(size_t)oc * 2340 + (256 + n) * 9 + ky * 3 + kx];
            }
        }
        op[n] = s;
    }
    ((float4*)btabT)[cs * 256 + oc] = o;
}

// -------- head weight pack + zero page ------------------------------------
__global__ void pack_head_kernel(const float* __restrict__ w_cls,
                                 const float* __restrict__ w_mean,
                                 float* __restrict__ wcp, float* __restrict__ wmp,
                                 ushort* __restrict__ zpg)
{
    const int oc = threadIdx.x;  // 256
    wcp[oc * 2]     = w_cls[oc];
    wcp[oc * 2 + 1] = w_cls[256 + oc];
    float4 m;
    m.x = w_mean[oc];       m.y = w_mean[256 + oc];
    m.z = w_mean[512 + oc]; m.w = w_mean[768 + oc];
    ((float4*)wmp)[oc] = m;
    if (oc < 32) zpg[oc] = 0;
}

// ------------------- big 3x3 conv: 256 -> 256, bf16 MFMA -------------------
// Block: 16x8 tile, one batch, 512 threads. Wave w owns oc slice
// [w*32, w*32+32) (i=2 frags of 16) and ALL 8 y-rows (j=8 frags).
// Full-depth input in LDS:
//   core [8c][40u=(10r x 4icb)][16x][16B] = 81,920 B
//   halo [8c][10r][4icb][2side][16B]      = 10,240 B  (ushort off 40960)
//   s_out [64 pos][264 oc-ushort]         = 33,792 B  (ushort off 46080)
// Total 125,952 B -> 1 block/CU, 2 waves/SIMD.
// Jobs loop inside the block over the resident input; weight streams per
// wave are DISJOINT (no cross-wave duplication of VMEM bytes).
__global__ __launch_bounds__(512, 2) void conv3x3_mfma(
    const ushort* __restrict__ inN,   // NHWC bf16 [b][TOT][256]
    const ushort* __restrict__ pw0, const ushort* __restrict__ pw1,
    const float* __restrict__ bias0, const float* __restrict__ bias1,
    ushort* __restrict__ out0, ushort* __restrict__ out1,
    const ushort* __restrict__ zpg,
    int jobs, int reluFlags, Tab tab)
{
    __shared__ __align__(16) ushort smem[62976];   // 125,952 B
    ushort* s_out = smem + 46080;                  // [64][264]

    const int tid = threadIdx.x;
    // XCD-aware bijective swizzle (grid % 8 == 0): contiguous logical chunk
    // per XCD -> halo-neighbor tiles share an L2.
    const int nper = (int)(gridDim.x >> 3);
    const int id = ((int)blockIdx.x & 7) * nper + ((int)blockIdx.x >> 3);

    const int bsum = tab.blkBase[5];
    const int bb = (id >= bsum) ? 1 : 0;
    int t = id - bsum * bb;
    int L = 0;
    while (t >= tab.blkBase[L + 1]) ++L;
    const int rel = t - tab.blkBase[L];
    const int tX = tab.tilesX[L];
    const int H = tab.H[L], W = tab.W5[L];
    const int y0 = (rel / tX) * 8;
    const int x0 = (rel % tX) * 16;
    const int poff = tab.poff[L];

    const int lane = tid & 63;
    const int wave = tid >> 6;       // 0..7 : 32-oc slice owner
    const int lm   = lane & 15;
    const int quad = lane >> 4;

    const size_t inBase = ((size_t)bb * TOT + poff) * 256;

    // ---- stage full-depth input tile (once) via global_load_lds ----
    {
        const int c = wave;          // each wave stages its own ic-chunk
#pragma unroll
        for (int kk = 0; kk < 10; ++kk) {        // row r = kk
            const int ug = kk * 4;               // 4 units (icb=quad) / instr
            const int yi = y0 - 1 + kk;
            const int xi = x0 + lm;
            const ushort* src = zpg;
            if (yi >= 0 && yi < H && xi < W)
                src = inN + inBase + ((size_t)yi * W + xi) * 256 + c * 32 + quad * 8;
            gl_lds16(src, &smem[(c * 40 + ug) * 128]);
        }
    }
    // halo: 640 16B pieces, layout [c][r][icb][side]
    auto haloStage = [&](int pbase) {
        const int p = pbase + lane;
        const int c = p / 80;
        const int rem = p - c * 80;
        const int r = rem >> 3;
        const int icb = (rem >> 1) & 3;
        const int side = rem & 1;
        const int yi = y0 - 1 + r;
        const int xi = side ? (x0 + 16) : (x0 - 1);
        const ushort* src = zpg;
        if (yi >= 0 && yi < H && xi >= 0 && xi < W)
            src = inN + inBase + ((size_t)yi * W + xi) * 256 + c * 32 + icb * 8;
        gl_lds16(src, &smem[40960 + pbase * 8]);
    };
    haloStage(wave * 64);
    if (wave < 2) haloStage(512 + wave * 64);
    __syncthreads();   // drains gl_lds; input is LDS-resident for all jobs

    // ---- jobs, sequential over the resident input ----
#pragma unroll 1
    for (int job = 0; job < jobs; ++job) {
        const ushort* pwj  = job ? pw1 : pw0;
        const float*  bsj  = job ? bias1 : bias0;
        ushort*       outj = job ? out1 : out0;
        const int relu = (reluFlags >> job) & 1;
        // wave-disjoint weight stream: blocks (tap,c,ocg=wave*2+i) of 1KB.
        const ushort* pwl = pwj + (size_t)(wave * 2) * 512 + lm * 32 + quad * 8;

        f32x4 acc[2][8];
#pragma unroll
        for (int i = 0; i < 2; ++i)
#pragma unroll
            for (int j = 0; j < 8; ++j)
                acc[i][j] = (f32x4){0.f, 0.f, 0.f, 0.f};

#pragma unroll 1
        for (int c = 0; c < 8; ++c) {
#pragma unroll
            for (int kx = 0; kx < 3; ++kx) {
                // weights for this (c,kx): 6 disjoint 1KB wave-loads
                short8 av[3][2];
#pragma unroll
                for (int ky = 0; ky < 3; ++ky) {
                    const ushort* pa = pwl + (size_t)((ky * 3 + kx) * 8 + c) * 8192;
                    av[ky][0] = *(const short8*)(pa);
                    av[ky][1] = *(const short8*)(pa + 512);
                }
                // input rows 0..9 (with x halo substitution)
                short8 bv[10];
#pragma unroll
                for (int r = 0; r < 10; ++r) {
                    const int u = r * 4 + quad;
                    const int lmx = lm + kx - 1;
                    int addr = ((c * 40 + u) * 16 + lmx) * 8;
                    if (kx == 0 && lm == 0)
                        addr = 40960 + (c * 80 + r * 8 + quad * 2 + 0) * 8;
                    if (kx == 2 && lm == 15)
                        addr = 40960 + (c * 80 + r * 8 + quad * 2 + 1) * 8;
                    bv[r] = *(const short8*)&smem[addr];
                }
#pragma unroll
                for (int ky = 0; ky < 3; ++ky)
#pragma unroll
                    for (int i = 0; i < 2; ++i)
#pragma unroll
                        for (int j = 0; j < 8; ++j)
                            acc[i][j] = __builtin_amdgcn_mfma_f32_16x16x32_bf16(
                                av[ky][i], bv[j + ky], acc[i][j], 0, 0, 0);
            }
        }

        // ---- epilogue: two 64-position halves through the LDS transpose ----
#pragma unroll 1
        for (int ph = 0; ph < 2; ++ph) {
            __syncthreads();   // prior s_out reads (or staging) complete
#pragma unroll
            for (int i = 0; i < 2; ++i) {
                const int ocl = wave * 32 + i * 16 + quad * 4;
                const float4 b4 = *(const float4*)(bsj + ocl);
#pragma unroll
                for (int j4 = 0; j4 < 4; ++j4) {
                    const f32x4 a = acc[i][ph * 4 + j4];
                    const int p2 = j4 * 16 + lm;
                    float v0 = a[0] + b4.x;
                    float v1 = a[1] + b4.y;
                    float v2 = a[2] + b4.z;
                    float v3 = a[3] + b4.w;
                    if (relu) {
                        v0 = fmaxf(v0, 0.f); v1 = fmaxf(v1, 0.f);
                        v2 = fmaxf(v2, 0.f); v3 = fmaxf(v3, 0.f);
                    }
                    ushort4 o;
                    o.x = f2bf(v0); o.y = f2bf(v1); o.z = f2bf(v2); o.w = f2bf(v3);
                    *(ushort4*)&s_out[p2 * 264 + ocl] = o;
                }
            }
            __syncthreads();
            // store: 64 positions x 256 oc = 512B contiguous per position
#pragma unroll
            for (int it = 0; it < 4; ++it) {
                const int idx = it * 512 + tid;
                const int p2  = idx >> 5;
                const int sgm = idx & 31;
                const int r = ph * 4 + (p2 >> 4);
                const int y = y0 + r, x = x0 + (p2 & 15);
                if (y < H && x < W) {
                    short8 w = *(const short8*)&s_out[p2 * 264 + sgm * 8];
                    __builtin_nontemporal_store(w,
                        (short8*)(outj + ((size_t)bb * TOT + poff
                                  + (size_t)y * W + x) * 256 + sgm * 8));
                }
            }
        }
    }
}

// ------- qy conv (256->4, 3x3) + softmax; NHWC h2; 4 lanes per position ----
__global__ __launch_bounds__(256) void qy_softmax_kernel(
    const ushort* __restrict__ h2, const ushort* __restrict__ pwqy, // [4][9][256]
    const float* __restrict__ bqy, float* __restrict__ mixv, Tab tab)
{
    const int tid = threadIdx.x;
    const int p = blockIdx.x * 64 + (tid >> 2);
    if (p >= TOT) return;
    const int q = tid & 3;
    const int b = blockIdx.z;
    int L = 0; while (p >= tab.poff[L + 1]) ++L;
    const int pos = p - tab.poff[L];
    const int W = tab.W5[L], H = tab.H[L];
    const int y = pos / W, x = pos - y * W;

    int  off[9];
    bool val[9];
#pragma unroll
    for (int ky = 0; ky < 3; ++ky)
#pragma unroll
        for (int kx = 0; kx < 3; ++kx) {
            const int t = ky * 3 + kx;
            const int yi = y + ky - 1, xi = x + kx - 1;
            val[t] = (yi >= 0 && yi < H && xi >= 0 && xi < W);
            off[t] = ((ky - 1) * W + (kx - 1)) * 256;
        }

    float a0 = 0.f, a1 = 0.f, a2 = 0.f, a3 = 0.f;
    const ushort* hp = h2 + ((size_t)b * TOT + p) * 256;
#pragma unroll 1
    for (int k = 0; k < 8; ++k) {
        const int sb = (k * 4 + q) * 8;
#pragma unroll
        for (int t = 0; t < 9; ++t) {
            if (!val[t]) continue;
            const short8 h8 = *(const short8*)(hp + off[t] + sb);
            float hv[8];
#pragma unroll
            for (int e = 0; e < 8; ++e) hv[e] = bf2f((ushort)h8[e]);
            const short8 w0 = *(const short8*)(pwqy + (0 * 9 + t) * 256 + sb);
            const short8 w1 = *(const short8*)(pwqy + (1 * 9 + t) * 256 + sb);
            const short8 w2 = *(const short8*)(pwqy + (2 * 9 + t) * 256 + sb);
            const short8 w3 = *(const short8*)(pwqy + (3 * 9 + t) * 256 + sb);
#pragma unroll
            for (int e = 0; e < 8; ++e) {
                a0 = fmaf(bf2f((ushort)w0[e]), hv[e], a0);
                a1 = fmaf(bf2f((ushort)w1[e]), hv[e], a1);
                a2 = fmaf(bf2f((ushort)w2[e]), hv[e], a2);
                a3 = fmaf(bf2f((ushort)w3[e]), hv[e], a3);
            }
        }
    }
    a0 += __shfl_xor(a0, 1); a0 += __shfl_xor(a0, 2);
    a1 += __shfl_xor(a1, 1); a1 += __shfl_xor(a1, 2);
    a2 += __shfl_xor(a2, 1); a2 += __shfl_xor(a2, 2);
    a3 += __shfl_xor(a3, 1); a3 += __shfl_xor(a3, 2);
    if (q == 0) {
        a0 += bqy[0]; a1 += bqy[1]; a2 += bqy[2]; a3 += bqy[3];
        const float mx = fmaxf(fmaxf(a0, a1), fmaxf(a2, a3));
        const float e0 = expf(a0 - mx), e1 = expf(a1 - mx);
        const float e2 = expf(a2 - mx), e3 = expf(a3 - mx);
        const float s = 1.f / (e0 + e1 + e2 + e3);
        float4 o; o.x = e0 * s; o.y = e1 * s; o.z = e2 * s; o.w = e3 * s;
        ((float4*)mixv)[(size_t)b * TOT + p] = o;
    }
}

// ------ final: T = sum_n mix_n*relu(u+bias_n); 6 heads; decode; clip -------
__global__ __launch_bounds__(256) void final_kernel(
    const float* __restrict__ mixv, const ushort* __restrict__ U,
    const float* __restrict__ btabT,
    const float* __restrict__ wcp, const float* __restrict__ wmp,
    const float* __restrict__ b_cls, const float* __restrict__ b_mean,
    const float* __restrict__ im_info,
    float* __restrict__ outp, Tab tab)
{
    const int tid = threadIdx.x;
    const int p = blockIdx.x * 64 + (tid >> 2);
    if (p >= TOT) return;
    const int q = tid & 3;
    const int b = blockIdx.z;
    int L = 0; while (p >= tab.poff[L + 1]) ++L;
    const int pos = p - tab.poff[L];
    const int W = tab.W5[L], H = tab.H[L];
    const int y = pos / W, x = pos - y * W;
    const int cy = (y == 0) ? 0 : ((y == H - 1) ? 2 : 1);
    const int cx = (x == 0) ? 0 : ((x == W - 1) ? 2 : 1);
    const float* bT = btabT + (size_t)(cy * 3 + cx) * 1024;

    const float4 mm = ((const float4*)mixv)[(size_t)b * TOT + p];
    const ushort* up = U + ((size_t)b * TOT + p) * 256;

    float sc0 = 0.f, sc1 = 0.f, D0 = 0.f, D1 = 0.f, D2 = 0.f, D3 = 0.f;
#pragma unroll 1
    for (int k = 0; k < 8; ++k) {
        const int seg = k * 4 + q;
        const short8 u8 = *(const short8*)(up + seg * 8);
#pragma unroll
        for (int e = 0; e < 8; ++e) {
            const int oc = seg * 8 + e;
            const float u = bf2f((ushort)u8[e]);
            const float4 bt = *(const float4*)(bT + oc * 4);
            float T =      mm.x * fmaxf(u + bt.x, 0.f);
            T = fmaf(mm.y, fmaxf(u + bt.y, 0.f), T);
            T = fmaf(mm.z, fmaxf(u + bt.z, 0.f), T);
            T = fmaf(mm.w, fmaxf(u + bt.w, 0.f), T);
            const float2 wc = *(const float2*)(wcp + oc * 2);
            const float4 wm = *(const float4*)(wmp + oc * 4);
            sc0 = fmaf(wc.x, T, sc0); sc1 = fmaf(wc.y, T, sc1);
            D0 = fmaf(wm.x, T, D0);   D1 = fmaf(wm.y, T, D1);
            D2 = fmaf(wm.z, T, D2);   D3 = fmaf(wm.w, T, D3);
        }
    }
    sc0 += __shfl_xor(sc0, 1); sc0 += __shfl_xor(sc0, 2);
    sc1 += __shfl_xor(sc1, 1); sc1 += __shfl_xor(sc1, 2);
    D0  += __shfl_xor(D0, 1);  D0  += __shfl_xor(D0, 2);
    D1  += __shfl_xor(D1, 1);  D1  += __shfl_xor(D1, 2);
    D2  += __shfl_xor(D2, 1);  D2  += __shfl_xor(D2, 2);
    D3  += __shfl_xor(D3, 1);  D3  += __shfl_xor(D3, 2);

    if (q == 0) {
        sc0 += b_cls[0]; sc1 += b_cls[1];
        D0 += b_mean[0]; D1 += b_mean[1]; D2 += b_mean[2]; D3 += b_mean[3];
        const float stride_ = (float)(64 >> L);
        const float aw  = stride_ * 8.f;
        const float acx = (x + 0.5f) * stride_;
        const float acy = (y + 0.5f) * stride_;
        const float cxx = acx + D0 * aw;
        const float cyy = acy + D1 * aw;
        const float e2 = fminf(fmaxf(D2, -10.f), 10.f);
        const float e3 = fminf(fmaxf(D3, -10.f), 10.f);
        const float bw = aw * expf(e2);
        const float bh = aw * expf(e3);
        const float imH = im_info[b * 6 + 0], imW = im_info[b * 6 + 1];
        const float x1 = fminf(fmaxf(cxx - 0.5f * bw, 0.f), imW);
        const float y1 = fminf(fmaxf(cyy - 0.5f * bh, 0.f), imH);
        const float x2 = fminf(fmaxf(cxx + 0.5f * bw, 0.f), imW);
        const float y2 = fminf(fmaxf(cyy + 0.5f * bh, 0.f), imH);
        float* op = outp + ((size_t)b * TOT + p) * 6;
        float2 w01; w01.x = x1; w01.y = y1;
        float2 w23; w23.x = x2; w23.y = y2;
        float2 w45; w45.x = sc0; w45.y = sc1;
        ((float2*)op)[0] = w01; ((float2*)op)[1] = w23; ((float2*)op)[2] = w45;
    }
}

// ---------------------------------------------------------------------------
extern "C" void kernel_launch(void* const* d_in, const int* in_sizes, int n_in,
                              void* d_out, int out_size, void* d_ws, size_t ws_size,
                              hipStream_t stream)
{
    (void)in_sizes; (void)n_in; (void)out_size; (void)ws_size;

    const float* im_info = (const float*)d_in[5];
    const float* w_qy1 = (const float*)d_in[6];
    const float* b_qy1 = (const float*)d_in[7];
    const float* w_qy2 = (const float*)d_in[8];
    const float* b_qy2 = (const float*)d_in[9];
    const float* w_qy  = (const float*)d_in[10];
    const float* b_qy  = (const float*)d_in[11];
    const float* w_rpn = (const float*)d_in[12];
    const float* b_rpn = (const float*)d_in[13];
    const float* w_cls = (const float*)d_in[14];
    const float* b_cls = (const float*)d_in[15];
    const float* w_mean= (const float*)d_in[16];
    const float* b_mean= (const float*)d_in[17];
    float* out = (float*)d_out;

    // ---- level tables ----
    Tab tab;
    const int Hs[5]  = {13, 25, 50, 100, 200};
    const int Ws5[5] = {19, 38, 76, 152, 304};
    int bsum = 0, psum = 0, csum = 0;
    for (int L = 0; L < 5; ++L) {
        tab.H[L] = Hs[L]; tab.W5[L] = Ws5[L];
        tab.tilesX[L] = (Ws5[L] + 15) / 16;
        tab.blkBase[L] = bsum;
        bsum += tab.tilesX[L] * ((Hs[L] + 7) / 8);
        tab.poff[L] = psum;
        tab.cvtBase[L] = csum;
        const int HW = Hs[L] * Ws5[L];
        psum += HW;
        csum += (HW + 63) / 64;
    }
    tab.blkBase[5] = bsum; tab.poff[5] = psum; tab.cvtBase[5] = csum;

    // ---- workspace layout (all 16B-aligned) ----
    const size_t BIGE = (size_t)2 * TOT * 256;   // 41,470,464 elems
    ushort* XBF  = (ushort*)d_ws;                // x NHWC; later aliased by H2
    ushort* H1   = XBF + BIGE;                   // h1 NHWC
    ushort* U    = H1 + BIGE;                    // U NHWC
    ushort* H2   = XBF;                          // h2 NHWC, aliases dead XN
    float*  MIXv = (float*)(U + BIGE);           // [b][TOT][4]
    float*  btabT= MIXv + (size_t)2 * TOT * 4;   // 9216
    float*  wcp  = btabT + 9216;                 // 512
    float*  wmp  = wcp + 512;                    // 1024
    ushort* PW1  = (ushort*)(wmp + 1024);
    ushort* PW2  = PW1 + 589824;
    ushort* PWR  = PW2 + 589824;
    ushort* PWQY = PWR + 589824;
    ushort* ZPG  = PWQY + 9216;                  // 32 ushort zero page

    // ---- prep ----
    cvtT_kernel<<<dim3(csum, 1, 2), 256, 0, stream>>>(
        (const float*)d_in[0], (const float*)d_in[1], (const float*)d_in[2],
        (const float*)d_in[3], (const float*)d_in[4], XBF, tab);
    pack_w_kernel<<<2304, 256, 0, stream>>>(w_qy1, PW1, 256);
    pack_w_kernel<<<2304, 256, 0, stream>>>(w_qy2, PW2, 256);
    pack_w_kernel<<<2304, 256, 0, stream>>>(w_rpn, PWR, 260);
    pack_qy_kernel<<<36, 256, 0, stream>>>(w_qy, PWQY);
    btabT_kernel<<<9, 256, 0, stream>>>(w_rpn, btabT);
    pack_head_kernel<<<1, 256, 0, stream>>>(w_cls, w_mean, wcp, wmp, ZPG);

    // ---- D1: conv1 (x->h1, relu) + convR (x->U); jobs inside block ----
    conv3x3_mfma<<<dim3(bsum * 2, 1, 1), 512, 0, stream>>>(
        XBF, PW1, PWR, b_qy1, b_rpn, H1, U, ZPG, /*jobs=*/2, /*reluFlags=*/0b01, tab);

    // ---- D2: conv2 (h1->h2, relu) ----
    conv3x3_mfma<<<dim3(bsum * 2, 1, 1), 512, 0, stream>>>(
        H1, PW2, PW2, b_qy2, b_qy2, H2, H2, ZPG, /*jobs=*/1, /*reluFlags=*/0b1, tab);

    // ---- D3: qy conv + softmax -> mix ----
    qy_softmax_kernel<<<dim3((TOT + 63) / 64, 1, 2), 256, 0, stream>>>(
        H2, PWQY, b_qy, MIXv, tab);

    // ---- D4: heads + mixture + decode + clip ----
    final_kernel<<<dim3((TOT + 63) / 64, 1, 2), 256, 0, stream>>>(
        MIXv, U, btabT, wcp, wmp, b_cls, b_mean, im_info, out, tab);
}

// Round 6
// 1171.372 us; speedup vs baseline: 2.5688x; 1.1736x over previous
//
#include <hip/hip_runtime.h>
#include <math.h>

// ---------------------------------------------------------------------------
// RPN GMM head, MI355X. Round 11: fix epilogue scratch spill (rule #20).
// R10 post-mortem: oc-partitioned waves worked (D1 1066->529us, MfmaUtil
// 15->32%) BUT WRITE jumped 162->571MB / FETCH 86->242MB: the epilogue read
// acc[i][ph*4+j4] with RUNTIME ph (unroll-1 loop) -> runtime-indexed
// ext_vector array -> compiler spills the whole acc to scratch at epilogue
// (64 f32/thread x 512thr x 1312blk x jobs ~ the 410MB write excess).
// Fix: epilogue as lambda epi(ph) called epi(0); epi(1); -> all acc indexing
// compile-time static. No other changes (attribution).
// conv3x3(concat[x, onehot_n], w_rpn) == conv3x3(x, w_rpn[:,:256]) + edge bias
// ---------------------------------------------------------------------------

typedef __attribute__((ext_vector_type(8))) short short8;
typedef __attribute__((ext_vector_type(4))) float f32x4;

#define TOT 80997

struct Tab {
    int tilesX[5];
    int blkBase[6];
    int H[5];
    int W5[5];
    int poff[6];
    int cvtBase[6];
};

static __device__ __forceinline__ ushort f2bf(float f) {
    union { float f; unsigned u; } x; x.f = f;
    unsigned r = (x.u + 0x7FFFu + ((x.u >> 16) & 1u)) >> 16;  // RNE
    return (ushort)r;
}
static __device__ __forceinline__ float bf2f(ushort u) {
    union { unsigned u; float f; } x; x.u = ((unsigned)u) << 16;
    return x.f;
}

static __device__ __forceinline__ void gl_lds16(const ushort* g, ushort* l) {
    __builtin_amdgcn_global_load_lds(
        (const __attribute__((address_space(1))) void*)g,
        (__attribute__((address_space(3))) void*)l, 16, 0, 0);
}

// -------- NCHW fp32 -> NHWC bf16 transpose-convert (64-pos x 256-ic tiles) --
__global__ __launch_bounds__(256) void cvtT_kernel(
    const float* __restrict__ f0, const float* __restrict__ f1,
    const float* __restrict__ f2, const float* __restrict__ f3,
    const float* __restrict__ f4, ushort* __restrict__ xn, Tab tab)
{
    __shared__ __align__(16) ushort s[64 * 264];
    const int tid = threadIdx.x;
    int t = blockIdx.x, L = 0;
    while (t >= tab.cvtBase[L + 1]) ++L;
    const int tile = t - tab.cvtBase[L];
    const int HW = tab.H[L] * tab.W5[L];
    const int pos0 = tile * 64;
    const int b = blockIdx.z;
    const float* fs[5] = {f0, f1, f2, f3, f4};
    const float* xp = fs[L] + (size_t)b * 256 * HW;

    const int p = tid & 63;
    const int icr = tid >> 6;
    const int pos = pos0 + p;
    for (int ic4 = 0; ic4 < 256; ic4 += 4) {
        const int ic = ic4 + icr;
        float v = 0.f;
        if (pos < HW) v = xp[(size_t)ic * HW + pos];
        s[p * 264 + ic] = f2bf(v);
    }
    __syncthreads();
    const int seg = tid & 31;
    for (int k = 0; k < 8; ++k) {
        const int pp = (tid >> 5) + k * 8;
        const int gpos = pos0 + pp;
        if (gpos < HW) {
            short8 v = *(const short8*)&s[pp * 264 + seg * 8];
            __builtin_nontemporal_store(v,
                (short8*)(xn + ((size_t)b * TOT + tab.poff[L] + gpos) * 256 + seg * 8));
        }
    }
}

// ---- weight pack: w[oc][ic][tap] fp32 -> pw[tap][c8][ocg16][lm16][q4][8] --
// idx = ((tap*8 + c)*16 + ocg)*512 + lm*32 + qe ; oc = ocg*16+lm, ic = c*32+qe
__global__ __launch_bounds__(256) void pack_w_kernel(
    const float* __restrict__ w, ushort* __restrict__ pw, int icfull)
{
    int idx = blockIdx.x * 256 + threadIdx.x;
    if (idx >= 589824) return;
    const int within = idx & 511;
    const int lm  = within >> 5;
    const int qe  = within & 31;
    const int rest = idx >> 9;
    const int ocg = rest & 15;
    const int tc  = rest >> 4;
    const int c   = tc & 7;
    const int tap = tc >> 3;
    const int oc = ocg * 16 + lm;
    const int ic = c * 32 + qe;
    pw[idx] = f2bf(w[((size_t)oc * icfull + ic) * 9 + tap]);
}

// -------- qy weight pack: wqy[n][ic][tap] fp32 -> pwqy[n][tap][ic] bf16 ----
__global__ __launch_bounds__(256) void pack_qy_kernel(
    const float* __restrict__ wqy, ushort* __restrict__ pwqy)
{
    int idx = blockIdx.x * 256 + threadIdx.x;   // 4*9*256 = 9216
    if (idx >= 9216) return;
    int ic = idx & 255;
    int t  = (idx >> 8) % 9;
    int n  = (idx >> 8) / 9;
    pwqy[idx] = f2bf(wqy[n * 2304 + ic * 9 + t]);
}

// ---- edge-bias table, transposed: btabT[case][oc][n] (float4 per oc) ------
__global__ __launch_bounds__(256) void btabT_kernel(
    const float* __restrict__ w_rpn, float* __restrict__ btabT)
{
    int idx = blockIdx.x * 256 + threadIdx.x;   // 9*256
    if (idx >= 2304) return;
    const int oc = idx & 255;
    const int cs = idx >> 8;
    const int cy = cs / 3, cx = cs % 3;
    float4 o;
    float* op = (float*)&o;
    for (int n = 0; n < 4; ++n) {
        float s = 0.f;
        for (int ky = 0; ky < 3; ++ky) {
            if (cy == 0 && ky == 0) continue;
            if (cy == 2 && ky == 2) continue;
            for (int kx = 0; kx < 3; ++kx) {
                if (cx == 0 && kx == 0) continue;
                if (cx == 2 && kx == 2) continue;
                s += w_rpn[(size_t)oc * 2340 + (256 + n) * 9 + ky * 3 + kx];
            }
        }
        op[n] = s;
    }
    ((float4*)btabT)[cs * 256 + oc] = o;
}

// -------- head weight pack + zero page ------------------------------------
__global__ void pack_head_kernel(const float* __restrict__ w_cls,
                                 const float* __restrict__ w_mean,
                                 float* __restrict__ wcp, float* __restrict__ wmp,
                                 ushort* __restrict__ zpg)
{
    const int oc = threadIdx.x;  // 256
    wcp[oc * 2]     = w_cls[oc];
    wcp[oc * 2 + 1] = w_cls[256 + oc];
    float4 m;
    m.x = w_mean[oc];       m.y = w_mean[256 + oc];
    m.z = w_mean[512 + oc]; m.w = w_mean[768 + oc];
    ((float4*)wmp)[oc] = m;
    if (oc < 32) zpg[oc] = 0;
}

// ------------------- big 3x3 conv: 256 -> 256, bf16 MFMA -------------------
// Block: 16x8 tile, one batch, 512 threads. Wave w owns oc slice
// [w*32, w*32+32) (i=2 frags of 16) and ALL 8 y-rows (j=8 frags).
// Full-depth input in LDS:
//   core [8c][40u=(10r x 4icb)][16x][16B] = 81,920 B
//   halo [8c][10r][4icb][2side][16B]      = 10,240 B  (ushort off 40960)
//   s_out [64 pos][264 oc-ushort]         = 33,792 B  (ushort off 46080)
// Total 125,952 B -> 1 block/CU, 2 waves/SIMD.
// Jobs loop inside the block over the resident input; weight streams per
// wave are DISJOINT (no cross-wave duplication of VMEM bytes).
__global__ __launch_bounds__(512, 2) void conv3x3_mfma(
    const ushort* __restrict__ inN,   // NHWC bf16 [b][TOT][256]
    const ushort* __restrict__ pw0, const ushort* __restrict__ pw1,
    const float* __restrict__ bias0, const float* __restrict__ bias1,
    ushort* __restrict__ out0, ushort* __restrict__ out1,
    const ushort* __restrict__ zpg,
    int jobs, int reluFlags, Tab tab)
{
    __shared__ __align__(16) ushort smem[62976];   // 125,952 B
    ushort* s_out = smem + 46080;                  // [64][264]

    const int tid = threadIdx.x;
    // XCD-aware bijective swizzle (grid % 8 == 0): contiguous logical chunk
    // per XCD -> halo-neighbor tiles share an L2.
    const int nper = (int)(gridDim.x >> 3);
    const int id = ((int)blockIdx.x & 7) * nper + ((int)blockIdx.x >> 3);

    const int bsum = tab.blkBase[5];
    const int bb = (id >= bsum) ? 1 : 0;
    int t = id - bsum * bb;
    int L = 0;
    while (t >= tab.blkBase[L + 1]) ++L;
    const int rel = t - tab.blkBase[L];
    const int tX = tab.tilesX[L];
    const int H = tab.H[L], W = tab.W5[L];
    const int y0 = (rel / tX) * 8;
    const int x0 = (rel % tX) * 16;
    const int poff = tab.poff[L];

    const int lane = tid & 63;
    const int wave = tid >> 6;       // 0..7 : 32-oc slice owner
    const int lm   = lane & 15;
    const int quad = lane >> 4;

    const size_t inBase = ((size_t)bb * TOT + poff) * 256;

    // ---- stage full-depth input tile (once) via global_load_lds ----
    {
        const int c = wave;          // each wave stages its own ic-chunk
#pragma unroll
        for (int kk = 0; kk < 10; ++kk) {        // row r = kk
            const int ug = kk * 4;               // 4 units (icb=quad) / instr
            const int yi = y0 - 1 + kk;
            const int xi = x0 + lm;
            const ushort* src = zpg;
            if (yi >= 0 && yi < H && xi < W)
                src = inN + inBase + ((size_t)yi * W + xi) * 256 + c * 32 + quad * 8;
            gl_lds16(src, &smem[(c * 40 + ug) * 128]);
        }
    }
    // halo: 640 16B pieces, layout [c][r][icb][side]
    auto haloStage = [&](int pbase) {
        const int p = pbase + lane;
        const int c = p / 80;
        const int rem = p - c * 80;
        const int r = rem >> 3;
        const int icb = (rem >> 1) & 3;
        const int side = rem & 1;
        const int yi = y0 - 1 + r;
        const int xi = side ? (x0 + 16) : (x0 - 1);
        const ushort* src = zpg;
        if (yi >= 0 && yi < H && xi >= 0 && xi < W)
            src = inN + inBase + ((size_t)yi * W + xi) * 256 + c * 32 + icb * 8;
        gl_lds16(src, &smem[40960 + pbase * 8]);
    };
    haloStage(wave * 64);
    if (wave < 2) haloStage(512 + wave * 64);
    __syncthreads();   // drains gl_lds; input is LDS-resident for all jobs

    // ---- jobs, sequential over the resident input ----
#pragma unroll 1
    for (int job = 0; job < jobs; ++job) {
        const ushort* pwj  = job ? pw1 : pw0;
        const float*  bsj  = job ? bias1 : bias0;
        ushort*       outj = job ? out1 : out0;
        const int relu = (reluFlags >> job) & 1;
        // wave-disjoint weight stream: blocks (tap,c,ocg=wave*2+i) of 1KB.
        const ushort* pwl = pwj + (size_t)(wave * 2) * 512 + lm * 32 + quad * 8;

        f32x4 acc[2][8];
#pragma unroll
        for (int i = 0; i < 2; ++i)
#pragma unroll
            for (int j = 0; j < 8; ++j)
                acc[i][j] = (f32x4){0.f, 0.f, 0.f, 0.f};

#pragma unroll 1
        for (int c = 0; c < 8; ++c) {
#pragma unroll
            for (int kx = 0; kx < 3; ++kx) {
                // weights for this (c,kx): 6 disjoint 1KB wave-loads
                short8 av[3][2];
#pragma unroll
                for (int ky = 0; ky < 3; ++ky) {
                    const ushort* pa = pwl + (size_t)((ky * 3 + kx) * 8 + c) * 8192;
                    av[ky][0] = *(const short8*)(pa);
                    av[ky][1] = *(const short8*)(pa + 512);
                }
                // input rows 0..9 (with x halo substitution)
                short8 bv[10];
#pragma unroll
                for (int r = 0; r < 10; ++r) {
                    const int u = r * 4 + quad;
                    const int lmx = lm + kx - 1;
                    int addr = ((c * 40 + u) * 16 + lmx) * 8;
                    if (kx == 0 && lm == 0)
                        addr = 40960 + (c * 80 + r * 8 + quad * 2 + 0) * 8;
                    if (kx == 2 && lm == 15)
                        addr = 40960 + (c * 80 + r * 8 + quad * 2 + 1) * 8;
                    bv[r] = *(const short8*)&smem[addr];
                }
#pragma unroll
                for (int ky = 0; ky < 3; ++ky)
#pragma unroll
                    for (int i = 0; i < 2; ++i)
#pragma unroll
                        for (int j = 0; j < 8; ++j)
                            acc[i][j] = __builtin_amdgcn_mfma_f32_16x16x32_bf16(
                                av[ky][i], bv[j + ky], acc[i][j], 0, 0, 0);
            }
        }

        // ---- epilogue: two 64-position halves; ph is COMPILE-TIME so all
        // acc[] indexing stays static (rule #20: no runtime-indexed frags) ---
        auto epi = [&](const int ph) {   // ph is a literal at both call sites
            __syncthreads();   // prior s_out reads (or staging) complete
#pragma unroll
            for (int i = 0; i < 2; ++i) {
                const int ocl = wave * 32 + i * 16 + quad * 4;
                const float4 b4 = *(const float4*)(bsj + ocl);
#pragma unroll
                for (int j4 = 0; j4 < 4; ++j4) {
                    const f32x4 a = acc[i][ph * 4 + j4];
                    const int p2 = j4 * 16 + lm;
                    float v0 = a[0] + b4.x;
                    float v1 = a[1] + b4.y;
                    float v2 = a[2] + b4.z;
                    float v3 = a[3] + b4.w;
                    if (relu) {
                        v0 = fmaxf(v0, 0.f); v1 = fmaxf(v1, 0.f);
                        v2 = fmaxf(v2, 0.f); v3 = fmaxf(v3, 0.f);
                    }
                    ushort4 o;
                    o.x = f2bf(v0); o.y = f2bf(v1); o.z = f2bf(v2); o.w = f2bf(v3);
                    *(ushort4*)&s_out[p2 * 264 + ocl] = o;
                }
            }
            __syncthreads();
            // store: 64 positions x 256 oc = 512B contiguous per position
#pragma unroll
            for (int it = 0; it < 4; ++it) {
                const int idx = it * 512 + tid;
                const int p2  = idx >> 5;
                const int sgm = idx & 31;
                const int r = ph * 4 + (p2 >> 4);
                const int y = y0 + r, x = x0 + (p2 & 15);
                if (y < H && x < W) {
                    short8 w = *(const short8*)&s_out[p2 * 264 + sgm * 8];
                    __builtin_nontemporal_store(w,
                        (short8*)(outj + ((size_t)bb * TOT + poff
                                  + (size_t)y * W + x) * 256 + sgm * 8));
                }
            }
        };
        epi(0);
        epi(1);
    }
}

// ------- qy conv (256->4, 3x3) + softmax; NHWC h2; 4 lanes per position ----
__global__ __launch_bounds__(256) void qy_softmax_kernel(
    const ushort* __restrict__ h2, const ushort* __restrict__ pwqy, // [4][9][256]
    const float* __restrict__ bqy, float* __restrict__ mixv, Tab tab)
{
    const int tid = threadIdx.x;
    const int p = blockIdx.x * 64 + (tid >> 2);
    if (p >= TOT) return;
    const int q = tid & 3;
    const int b = blockIdx.z;
    int L = 0; while (p >= tab.poff[L + 1]) ++L;
    const int pos = p - tab.poff[L];
    const int W = tab.W5[L], H = tab.H[L];
    const int y = pos / W, x = pos - y * W;

    int  off[9];
    bool val[9];
#pragma unroll
    for (int ky = 0; ky < 3; ++ky)
#pragma unroll
        for (int kx = 0; kx < 3; ++kx) {
            const int t = ky * 3 + kx;
            const int yi = y + ky - 1, xi = x + kx - 1;
            val[t] = (yi >= 0 && yi < H && xi >= 0 && xi < W);
            off[t] = ((ky - 1) * W + (kx - 1)) * 256;
        }

    float a0 = 0.f, a1 = 0.f, a2 = 0.f, a3 = 0.f;
    const ushort* hp = h2 + ((size_t)b * TOT + p) * 256;
#pragma unroll 1
    for (int k = 0; k < 8; ++k) {
        const int sb = (k * 4 + q) * 8;
#pragma unroll
        for (int t = 0; t < 9; ++t) {
            if (!val[t]) continue;
            const short8 h8 = *(const short8*)(hp + off[t] + sb);
            float hv[8];
#pragma unroll
            for (int e = 0; e < 8; ++e) hv[e] = bf2f((ushort)h8[e]);
            const short8 w0 = *(const short8*)(pwqy + (0 * 9 + t) * 256 + sb);
            const short8 w1 = *(const short8*)(pwqy + (1 * 9 + t) * 256 + sb);
            const short8 w2 = *(const short8*)(pwqy + (2 * 9 + t) * 256 + sb);
            const short8 w3 = *(const short8*)(pwqy + (3 * 9 + t) * 256 + sb);
#pragma unroll
            for (int e = 0; e < 8; ++e) {
                a0 = fmaf(bf2f((ushort)w0[e]), hv[e], a0);
                a1 = fmaf(bf2f((ushort)w1[e]), hv[e], a1);
                a2 = fmaf(bf2f((ushort)w2[e]), hv[e], a2);
                a3 = fmaf(bf2f((ushort)w3[e]), hv[e], a3);
            }
        }
    }
    a0 += __shfl_xor(a0, 1); a0 += __shfl_xor(a0, 2);
    a1 += __shfl_xor(a1, 1); a1 += __shfl_xor(a1, 2);
    a2 += __shfl_xor(a2, 1); a2 += __shfl_xor(a2, 2);
    a3 += __shfl_xor(a3, 1); a3 += __shfl_xor(a3, 2);
    if (q == 0) {
        a0 += bqy[0]; a1 += bqy[1]; a2 += bqy[2]; a3 += bqy[3];
        const float mx = fmaxf(fmaxf(a0, a1), fmaxf(a2, a3));
        const float e0 = expf(a0 - mx), e1 = expf(a1 - mx);
        const float e2 = expf(a2 - mx), e3 = expf(a3 - mx);
        const float s = 1.f / (e0 + e1 + e2 + e3);
        float4 o; o.x = e0 * s; o.y = e1 * s; o.z = e2 * s; o.w = e3 * s;
        ((float4*)mixv)[(size_t)b * TOT + p] = o;
    }
}

// ------ final: T = sum_n mix_n*relu(u+bias_n); 6 heads; decode; clip -------
__global__ __launch_bounds__(256) void final_kernel(
    const float* __restrict__ mixv, const ushort* __restrict__ U,
    const float* __restrict__ btabT,
    const float* __restrict__ wcp, const float* __restrict__ wmp,
    const float* __restrict__ b_cls, const float* __restrict__ b_mean,
    const float* __restrict__ im_info,
    float* __restrict__ outp, Tab tab)
{
    const int tid = threadIdx.x;
    const int p = blockIdx.x * 64 + (tid >> 2);
    if (p >= TOT) return;
    const int q = tid & 3;
    const int b = blockIdx.z;
    int L = 0; while (p >= tab.poff[L + 1]) ++L;
    const int pos = p - tab.poff[L];
    const int W = tab.W5[L], H = tab.H[L];
    const int y = pos / W, x = pos - y * W;
    const int cy = (y == 0) ? 0 : ((y == H - 1) ? 2 : 1);
    const int cx = (x == 0) ? 0 : ((x == W - 1) ? 2 : 1);
    const float* bT = btabT + (size_t)(cy * 3 + cx) * 1024;

    const float4 mm = ((const float4*)mixv)[(size_t)b * TOT + p];
    const ushort* up = U + ((size_t)b * TOT + p) * 256;

    float sc0 = 0.f, sc1 = 0.f, D0 = 0.f, D1 = 0.f, D2 = 0.f, D3 = 0.f;
#pragma unroll 1
    for (int k = 0; k < 8; ++k) {
        const int seg = k * 4 + q;
        const short8 u8 = *(const short8*)(up + seg * 8);
#pragma unroll
        for (int e = 0; e < 8; ++e) {
            const int oc = seg * 8 + e;
            const float u = bf2f((ushort)u8[e]);
            const float4 bt = *(const float4*)(bT + oc * 4);
            float T =      mm.x * fmaxf(u + bt.x, 0.f);
            T = fmaf(mm.y, fmaxf(u + bt.y, 0.f), T);
            T = fmaf(mm.z, fmaxf(u + bt.z, 0.f), T);
            T = fmaf(mm.w, fmaxf(u + bt.w, 0.f), T);
            const float2 wc = *(const float2*)(wcp + oc * 2);
            const float4 wm = *(const float4*)(wmp + oc * 4);
            sc0 = fmaf(wc.x, T, sc0); sc1 = fmaf(wc.y, T, sc1);
            D0 = fmaf(wm.x, T, D0);   D1 = fmaf(wm.y, T, D1);
            D2 = fmaf(wm.z, T, D2);   D3 = fmaf(wm.w, T, D3);
        }
    }
    sc0 += __shfl_xor(sc0, 1); sc0 += __shfl_xor(sc0, 2);
    sc1 += __shfl_xor(sc1, 1); sc1 += __shfl_xor(sc1, 2);
    D0  += __shfl_xor(D0, 1);  D0  += __shfl_xor(D0, 2);
    D1  += __shfl_xor(D1, 1);  D1  += __shfl_xor(D1, 2);
    D2  += __shfl_xor(D2, 1);  D2  += __shfl_xor(D2, 2);
    D3  += __shfl_xor(D3, 1);  D3  += __shfl_xor(D3, 2);

    if (q == 0) {
        sc0 += b_cls[0]; sc1 += b_cls[1];
        D0 += b_mean[0]; D1 += b_mean[1]; D2 += b_mean[2]; D3 += b_mean[3];
        const float stride_ = (float)(64 >> L);
        const float aw  = stride_ * 8.f;
        const float acx = (x + 0.5f) * stride_;
        const float acy = (y + 0.5f) * stride_;
        const float cxx = acx + D0 * aw;
        const float cyy = acy + D1 * aw;
        const float e2 = fminf(fmaxf(D2, -10.f), 10.f);
        const float e3 = fminf(fmaxf(D3, -10.f), 10.f);
        const float bw = aw * expf(e2);
        const float bh = aw * expf(e3);
        const float imH = im_info[b * 6 + 0], imW = im_info[b * 6 + 1];
        const float x1 = fminf(fmaxf(cxx - 0.5f * bw, 0.f), imW);
        const float y1 = fminf(fmaxf(cyy - 0.5f * bh, 0.f), imH);
        const float x2 = fminf(fmaxf(cxx + 0.5f * bw, 0.f), imW);
        const float y2 = fminf(fmaxf(cyy + 0.5f * bh, 0.f), imH);
        float* op = outp + ((size_t)b * TOT + p) * 6;
        float2 w01; w01.x = x1; w01.y = y1;
        float2 w23; w23.x = x2; w23.y = y2;
        float2 w45; w45.x = sc0; w45.y = sc1;
        ((float2*)op)[0] = w01; ((float2*)op)[1] = w23; ((float2*)op)[2] = w45;
    }
}

// ---------------------------------------------------------------------------
extern "C" void kernel_launch(void* const* d_in, const int* in_sizes, int n_in,
                              void* d_out, int out_size, void* d_ws, size_t ws_size,
                              hipStream_t stream)
{
    (void)in_sizes; (void)n_in; (void)out_size; (void)ws_size;

    const float* im_info = (const float*)d_in[5];
    const float* w_qy1 = (const float*)d_in[6];
    const float* b_qy1 = (const float*)d_in[7];
    const float* w_qy2 = (const float*)d_in[8];
    const float* b_qy2 = (const float*)d_in[9];
    const float* w_qy  = (const float*)d_in[10];
    const float* b_qy  = (const float*)d_in[11];
    const float* w_rpn = (const float*)d_in[12];
    const float* b_rpn = (const float*)d_in[13];
    const float* w_cls = (const float*)d_in[14];
    const float* b_cls = (const float*)d_in[15];
    const float* w_mean= (const float*)d_in[16];
    const float* b_mean= (const float*)d_in[17];
    float* out = (float*)d_out;

    // ---- level tables ----
    Tab tab;
    const int Hs[5]  = {13, 25, 50, 100, 200};
    const int Ws5[5] = {19, 38, 76, 152, 304};
    int bsum = 0, psum = 0, csum = 0;
    for (int L = 0; L < 5; ++L) {
        tab.H[L] = Hs[L]; tab.W5[L] = Ws5[L];
        tab.tilesX[L] = (Ws5[L] + 15) / 16;
        tab.blkBase[L] = bsum;
        bsum += tab.tilesX[L] * ((Hs[L] + 7) / 8);
        tab.poff[L] = psum;
        tab.cvtBase[L] = csum;
        const int HW = Hs[L] * Ws5[L];
        psum += HW;
        csum += (HW + 63) / 64;
    }
    tab.blkBase[5] = bsum; tab.poff[5] = psum; tab.cvtBase[5] = csum;

    // ---- workspace layout (all 16B-aligned) ----
    const size_t BIGE = (size_t)2 * TOT * 256;   // 41,470,464 elems
    ushort* XBF  = (ushort*)d_ws;                // x NHWC; later aliased by H2
    ushort* H1   = XBF + BIGE;                   // h1 NHWC
    ushort* U    = H1 + BIGE;                    // U NHWC
    ushort* H2   = XBF;                          // h2 NHWC, aliases dead XN
    float*  MIXv = (float*)(U + BIGE);           // [b][TOT][4]
    float*  btabT= MIXv + (size_t)2 * TOT * 4;   // 9216
    float*  wcp  = btabT + 9216;                 // 512
    float*  wmp  = wcp + 512;                    // 1024
    ushort* PW1  = (ushort*)(wmp + 1024);
    ushort* PW2  = PW1 + 589824;
    ushort* PWR  = PW2 + 589824;
    ushort* PWQY = PWR + 589824;
    ushort* ZPG  = PWQY + 9216;                  // 32 ushort zero page

    // ---- prep ----
    cvtT_kernel<<<dim3(csum, 1, 2), 256, 0, stream>>>(
        (const float*)d_in[0], (const float*)d_in[1], (const float*)d_in[2],
        (const float*)d_in[3], (const float*)d_in[4], XBF, tab);
    pack_w_kernel<<<2304, 256, 0, stream>>>(w_qy1, PW1, 256);
    pack_w_kernel<<<2304, 256, 0, stream>>>(w_qy2, PW2, 256);
    pack_w_kernel<<<2304, 256, 0, stream>>>(w_rpn, PWR, 260);
    pack_qy_kernel<<<36, 256, 0, stream>>>(w_qy, PWQY);
    btabT_kernel<<<9, 256, 0, stream>>>(w_rpn, btabT);
    pack_head_kernel<<<1, 256, 0, stream>>>(w_cls, w_mean, wcp, wmp, ZPG);

    // ---- D1: conv1 (x->h1, relu) + convR (x->U); jobs inside block ----
    conv3x3_mfma<<<dim3(bsum * 2, 1, 1), 512, 0, stream>>>(
        XBF, PW1, PWR, b_qy1, b_rpn, H1, U, ZPG, /*jobs=*/2, /*reluFlags=*/0b01, tab);

    // ---- D2: conv2 (h1->h2, relu) ----
    conv3x3_mfma<<<dim3(bsum * 2, 1, 1), 512, 0, stream>>>(
        H1, PW2, PW2, b_qy2, b_qy2, H2, H2, ZPG, /*jobs=*/1, /*reluFlags=*/0b1, tab);

    // ---- D3: qy conv + softmax -> mix ----
    qy_softmax_kernel<<<dim3((TOT + 63) / 64, 1, 2), 256, 0, stream>>>(
        H2, PWQY, b_qy, MIXv, tab);

    // ---- D4: heads + mixture + decode + clip ----
    final_kernel<<<dim3((TOT + 63) / 64, 1, 2), 256, 0, stream>>>(
        MIXv, U, btabT, wcp, wmp, b_cls, b_mean, im_info, out, tab);
}